// Round 6
// baseline (1474.121 us; speedup 1.0000x reference)
//
#include <hip/hip_runtime.h>
#include <math.h>

// ---------------------------------------------------------------------------
// MeshGraphUnet2 forward on gfx950.  Round 5: fused up-agg (no cat buffer),
// LN fused into up MFMA gemm3, score fused into down ln (bit-identical trees),
// self-prefix scan/tie kernels (fewer dispatches). Down path f32 exact.
// ---------------------------------------------------------------------------

typedef unsigned short u16;
typedef short bf16x8 __attribute__((ext_vector_type(8)));
typedef float f32x4 __attribute__((ext_vector_type(4)));

__device__ __forceinline__ unsigned int fkey(float f) {
  unsigned int b = __float_as_uint(f);
  return (b & 0x80000000u) ? ~b : (b | 0x80000000u);  // monotonic float->uint
}

__device__ __forceinline__ float gelu_f(float v) {
  return 0.5f * v * (1.0f + erff(v * 0.70710678118654752f));
}

__device__ __forceinline__ u16 f2bf(float f) {
  unsigned u = __float_as_uint(f);
  u = (u + 0x7FFFu + ((u >> 16) & 1u)) >> 16;  // round-nearest-even
  return (u16)u;
}
__device__ __forceinline__ float bf2f(u16 u) {
  return __uint_as_float(((unsigned)u) << 16);
}

// ---- level-0 scoring: key[i] = (float)(x[i,:].w) f64, valt = tanh(d/||w||)
__global__ void score_kernel(const float* __restrict__ x, const float* __restrict__ w,
                             float* __restrict__ key, float* __restrict__ valt, int n) {
  int wave = threadIdx.x >> 6, lane = threadIdx.x & 63;
  int i = blockIdx.x * 4 + wave;
  if (i >= n) return;
  float2 xv = *(const float2*)&x[(size_t)i * 128 + lane * 2];
  float2 wv = *(const float2*)&w[lane * 2];
  double d  = (double)xv.x * wv.x + (double)xv.y * wv.y;
  double nw = (double)wv.x * wv.x + (double)wv.y * wv.y;
  for (int o = 32; o; o >>= 1) { d += __shfl_down(d, o, 64); nw += __shfl_down(nw, o, 64); }
  if (lane == 0) {
    key[i]  = (float)d;
    valt[i] = (float)tanh(d / sqrt(nw));
  }
}

// precompute sqrt(||w||^2) per level with the SAME reduction tree as score_kernel
__global__ void wnorm_kernel(const float* __restrict__ poolw, double* __restrict__ sqn) {
  int lane = threadIdx.x & 63;
  for (int l = 0; l < 3; ++l) {
    float2 wv = *(const float2*)&poolw[l * 128 + lane * 2];
    double nw = (double)wv.x * wv.x + (double)wv.y * wv.y;
    for (int o = 32; o; o >>= 1) nw += __shfl_down(nw, o, 64);
    if (lane == 0) sqn[l] = sqrt(nw);
  }
}

// x0 f32 -> bf16
__global__ void xconv_kernel(const float* __restrict__ x, u16* __restrict__ xb, int n) {
  int gid = blockIdx.x * 256 + threadIdx.x;
  if (gid >= n * 32) return;
  float4 a = *(const float4*)&x[(size_t)gid * 4];
  *(ushort4*)&xb[(size_t)gid * 4] = make_ushort4(f2bf(a.x), f2bf(a.y), f2bf(a.z), f2bf(a.w));
}

// ---- histograms with fused chunk sums (csum[256] via atomics) ----
__global__ void hist_hi_kernel(const float* __restrict__ key, int* __restrict__ hist,
                               int* __restrict__ csum, int n) {
  int i = blockIdx.x * 256 + threadIdx.x;
  if (i >= n) return;
  unsigned b = fkey(key[i]) >> 16;
  atomicAdd(&hist[b], 1);
  atomicAdd(&csum[b >> 8], 1);
}

__global__ void hist_lo_kernel(const float* __restrict__ key, const int* __restrict__ meta,
                               int* __restrict__ hist, int* __restrict__ csum, int n) {
  int i = blockIdx.x * 256 + threadIdx.x;
  if (i >= n) return;
  unsigned u = fkey(key[i]);
  if ((u >> 16) == (unsigned)meta[0]) {
    unsigned b = u & 0xFFFFu;
    atomicAdd(&hist[b], 1);
    atomicAdd(&csum[b >> 8], 1);
  }
}

__global__ void find_hi2_kernel(const int* __restrict__ hist, const int* __restrict__ csum,
                                int* __restrict__ meta, int k) {
  __shared__ int s[256];
  __shared__ int cSh, cumSh;
  int t = threadIdx.x;
  s[t] = csum[t];
  __syncthreads();
  if (t == 0) {
    int cum = 0, c = 0;
    for (int i = 255; i >= 0; --i) {
      if (cum + s[i] >= k) { c = i; break; }
      cum += s[i];
    }
    cSh = c; cumSh = cum;
  }
  __syncthreads();
  int c = cSh;
  s[t] = hist[c * 256 + t];
  __syncthreads();
  if (t == 0) {
    int cum = cumSh;
    for (int b = 255; b >= 0; --b) {
      int v = s[b];
      if (cum + v >= k) { meta[0] = c * 256 + b; meta[1] = k - cum; break; }
      cum += v;
    }
  }
}

__global__ void find_lo2_kernel(const int* __restrict__ hist, const int* __restrict__ csum,
                                int* __restrict__ meta) {
  __shared__ int s[256];
  __shared__ int cSh, cumSh;
  int t = threadIdx.x;
  int m = meta[1], B = meta[0];
  s[t] = csum[t];
  __syncthreads();
  if (t == 0) {
    int cum = 0, c = 0;
    for (int i = 255; i >= 0; --i) {
      if (cum + s[i] >= m) { c = i; break; }
      cum += s[i];
    }
    cSh = c; cumSh = cum;
  }
  __syncthreads();
  int c = cSh;
  s[t] = hist[c * 256 + t];
  __syncthreads();
  if (t == 0) {
    int cum = cumSh;
    for (int b = 255; b >= 0; --b) {
      int v = s[b];
      if (cum + v >= m) {
        meta[3] = (int)((((unsigned)B) << 16) | (unsigned)(c * 256 + b));
        meta[4] = m - cum;
        break;
      }
      cum += v;
    }
    meta[5] = 0;
  }
}

__global__ void tie_count_kernel(const float* __restrict__ key, const int* __restrict__ meta,
                                 int* __restrict__ tcnt, int n) {
  __shared__ int cnt[4];
  unsigned uT = (unsigned)meta[3];
  int i = blockIdx.x * 256 + threadIdx.x;
  bool tie = (i < n) && (fkey(key[i]) == uT);
  unsigned long long m = __ballot(tie);
  int lane = threadIdx.x & 63, w = threadIdx.x >> 6;
  if (lane == 0) cnt[w] = __popcll(m);
  __syncthreads();
  if (threadIdx.x == 0) tcnt[blockIdx.x] = cnt[0] + cnt[1] + cnt[2] + cnt[3];
}

// tie mark with self-computed block prefix (nb <= 256 guaranteed)
__global__ void tie_mark_kernel(const float* __restrict__ key, const int* __restrict__ meta,
                                const int* __restrict__ tcnt, unsigned char* __restrict__ selt,
                                int n) {
  __shared__ int red[256];
  __shared__ int woff[4];
  int t = threadIdx.x;
  red[t] = (t < (int)blockIdx.x) ? tcnt[t] : 0;
  __syncthreads();
  for (int s = 128; s; s >>= 1) {
    if (t < s) red[t] += red[t + s];
    __syncthreads();
  }
  int blockbase = red[0];
  unsigned uT = (unsigned)meta[3];
  int tsel = meta[4];
  int i = blockIdx.x * 256 + t;
  bool tie = (i < n) && (fkey(key[i]) == uT);
  unsigned long long m = __ballot(tie);
  int lane = t & 63, w = t >> 6;
  if (lane == 0) woff[w] = __popcll(m);
  __syncthreads();
  if (t == 0) {
    int c = 0;
    for (int q = 0; q < 4; ++q) { int v = woff[q]; woff[q] = c; c += v; }
  }
  __syncthreads();
  if (tie) {
    int pre = __popcll(m & ((1ull << lane) - 1ull));
    int rank = blockbase + woff[w] + pre;
    selt[i] = (rank < tsel) ? 1 : 0;
  }
}

__global__ void select_kernel(const float* __restrict__ key, const float* __restrict__ valt,
                              const unsigned char* __restrict__ selt, int* __restrict__ meta,
                              int* __restrict__ perm, float* __restrict__ vals,
                              int* __restrict__ nmap, int n, int k) {
  int i = blockIdx.x * 256 + threadIdx.x;
  if (i > n) return;
  if (i == n) { nmap[n] = k; return; }
  unsigned u  = fkey(key[i]);
  unsigned uT = (unsigned)meta[3];
  bool sel = (u > uT) || (u == uT && selt[i] != 0);
  if (sel) {
    int slot = atomicAdd(&meta[5], 1);
    perm[slot] = i; vals[slot] = valt[i]; nmap[i] = slot;
  } else {
    nmap[i] = k;
  }
}

__global__ void pool_kernel(const float* __restrict__ x, const int* __restrict__ perm,
                            const float* __restrict__ vals, float* __restrict__ xp, int k) {
  int gid = blockIdx.x * 256 + threadIdx.x;
  int t = gid >> 5;
  if (t >= k) return;
  int c = (gid & 31) << 2;
  float v = vals[t];
  float4 a = *(const float4*)&x[(size_t)perm[t] * 128 + c];
  a.x *= v; a.y *= v; a.z *= v; a.w *= v;
  *(float4*)&xp[(size_t)t * 128 + c] = a;
}

// remap + degree count fused (deg zeroed before)
__global__ void remap_deg_kernel(const int* __restrict__ s_in, const int* __restrict__ r_in,
                                 const int* __restrict__ nmap, int* __restrict__ s_out,
                                 int* __restrict__ r_out, int* __restrict__ deg, int E, int k) {
  int e = blockIdx.x * 256 + threadIdx.x;
  if (e >= E) return;
  int a = nmap[s_in[e]], b = nmap[r_in[e]];
  if (a == k || b == k) { a = k; b = k; }
  s_out[e] = a; r_out[e] = b;
  if (a < k) { atomicAdd(&deg[b], 1); atomicAdd(&deg[a], 1); }
}

__global__ void deg_kernel(const int* __restrict__ s, const int* __restrict__ r,
                           int* __restrict__ deg, int E, int n) {
  int e = blockIdx.x * 256 + threadIdx.x;
  if (e >= E) return;
  int ss = s[e];
  if (ss >= n) return;
  int rr = r[e];
  atomicAdd(&deg[rr], 1);
  atomicAdd(&deg[ss], 1);
}

// ---- 2-pass parallel exclusive scan (self-prefix final; nb <= 256) ----
__global__ void scan_part_kernel(const int* __restrict__ deg, int* __restrict__ bsum, int n) {
  __shared__ int l[256];
  int i = blockIdx.x * 256 + threadIdx.x;
  l[threadIdx.x] = (i < n) ? deg[i] : 0;
  __syncthreads();
  for (int s = 128; s; s >>= 1) {
    if (threadIdx.x < s) l[threadIdx.x] += l[threadIdx.x + s];
    __syncthreads();
  }
  if (threadIdx.x == 0) bsum[blockIdx.x] = l[0];
}

__global__ void scan_final_kernel(const int* __restrict__ deg, const int* __restrict__ bsum,
                                  int* __restrict__ off, int* __restrict__ cur, int n) {
  __shared__ int red[256];
  __shared__ int l[256];
  int i = blockIdx.x * 256 + threadIdx.x;
  int t = threadIdx.x;
  red[t] = (t < (int)blockIdx.x) ? bsum[t] : 0;
  __syncthreads();
  for (int s = 128; s; s >>= 1) {
    if (t < s) red[t] += red[t + s];
    __syncthreads();
  }
  int base = red[0];
  int v = (i < n) ? deg[i] : 0;
  l[t] = v;
  __syncthreads();
#pragma unroll
  for (int s = 1; s < 256; s <<= 1) {
    int add = (t >= s) ? l[t - s] : 0;
    __syncthreads();
    l[t] += add;
    __syncthreads();
  }
  int incl = l[t];
  if (i < n) {
    int e = base + incl - v;
    off[i] = e; cur[i] = e;
    if (i == n - 1) off[n] = base + incl;
  }
}

__global__ void csr_scatter_kernel(const int* __restrict__ s, const int* __restrict__ r,
                                   int* __restrict__ cur, int* __restrict__ idx, int E, int n) {
  int e = blockIdx.x * 256 + threadIdx.x;
  if (e >= E) return;
  int ss = s[e];
  if (ss >= n) return;
  int rr = r[e];
  idx[atomicAdd(&cur[rr], 1)] = ss;
  idx[atomicAdd(&cur[ss], 1)] = rr;
}

// XCD-partitioned scatter (8 node-range groups, group = blockIdx&7)
__global__ void csr_scatter_part_kernel(const int* __restrict__ s, const int* __restrict__ r,
                                        int* __restrict__ cur, int* __restrict__ idx,
                                        int E, int n, int rshift) {
  int g = blockIdx.x & 7;
  int nb = gridDim.x >> 3;
  int bb = blockIdx.x >> 3;
  int lo = g << rshift, hi = (g + 1) << rshift;
  int stride = nb * 256;
  for (int e = bb * 256 + threadIdx.x; e < E; e += stride) {
    int ss = s[e];
    if (ss >= n) continue;
    int rr = r[e];
    if (rr >= lo && rr < hi) idx[atomicAdd(&cur[rr], 1)] = ss;
    if (ss >= lo && ss < hi) idx[atomicAdd(&cur[ss], 1)] = rr;
  }
}

// ---- down-path f32 aggregation (C=128) ----
__global__ void agg_kernel(const float* __restrict__ x, const int* __restrict__ off,
                           const int* __restrict__ idx, float* __restrict__ agg, int n) {
  int wave = threadIdx.x >> 6, lane = threadIdx.x & 63;
  int v = blockIdx.x * 4 + wave;
  if (v >= n) return;
  int lo = off[v], hi = off[v + 1];
  int c = lane * 2;
  float ax = 0.f, ay = 0.f;
  int j = lo;
  for (; j + 4 <= hi; j += 4) {
    int u0 = idx[j], u1 = idx[j + 1], u2 = idx[j + 2], u3 = idx[j + 3];
    float2 a0 = *(const float2*)&x[(size_t)u0 * 128 + c];
    float2 a1 = *(const float2*)&x[(size_t)u1 * 128 + c];
    float2 a2 = *(const float2*)&x[(size_t)u2 * 128 + c];
    float2 a3 = *(const float2*)&x[(size_t)u3 * 128 + c];
    ax += a0.x + a1.x + a2.x + a3.x;
    ay += a0.y + a1.y + a2.y + a3.y;
  }
  for (; j < hi; ++j) {
    int u = idx[j];
    float2 a = *(const float2*)&x[(size_t)u * 128 + c];
    ax += a.x; ay += a.y;
  }
  float2 o; o.x = ax; o.y = ay;
  *(float2*)&agg[(size_t)v * 128 + c] = o;
}

// ---- fused up-path aggregation: agg[v] = [ sum res_bf[u] | sum up(u) ] ----
// up(u) = xd_bf[nmap[u]] if selected else 0. Lanes 0-31 do res half, 32-63 up half.
__global__ void agg_up_kernel(const u16* __restrict__ res_bf, const u16* __restrict__ xd_bf,
                              const int* __restrict__ nmapL, const int* __restrict__ off,
                              const int* __restrict__ idx, u16* __restrict__ agg, int n, int k) {
  int wave = threadIdx.x >> 6, lane = threadIdx.x & 63;
  int v = blockIdx.x * 4 + wave;
  if (v >= n) return;
  int lo = off[v], hi = off[v + 1];
  bool hiHalf = lane >= 32;
  int c4 = (lane & 31) << 2;
  float a0 = 0.f, a1 = 0.f, a2 = 0.f, a3 = 0.f;
  int j = lo;
  for (; j + 4 <= hi; j += 4) {
    int u0 = idx[j], u1 = idx[j + 1], u2 = idx[j + 2], u3 = idx[j + 3];
    if (!hiHalf) {
      ushort4 b0 = *(const ushort4*)&res_bf[(size_t)u0 * 128 + c4];
      ushort4 b1 = *(const ushort4*)&res_bf[(size_t)u1 * 128 + c4];
      ushort4 b2 = *(const ushort4*)&res_bf[(size_t)u2 * 128 + c4];
      ushort4 b3 = *(const ushort4*)&res_bf[(size_t)u3 * 128 + c4];
      a0 += bf2f(b0.x) + bf2f(b1.x) + bf2f(b2.x) + bf2f(b3.x);
      a1 += bf2f(b0.y) + bf2f(b1.y) + bf2f(b2.y) + bf2f(b3.y);
      a2 += bf2f(b0.z) + bf2f(b1.z) + bf2f(b2.z) + bf2f(b3.z);
      a3 += bf2f(b0.w) + bf2f(b1.w) + bf2f(b2.w) + bf2f(b3.w);
    } else {
      int t0 = nmapL[u0], t1 = nmapL[u1], t2 = nmapL[u2], t3 = nmapL[u3];
      if (t0 < k) { ushort4 b = *(const ushort4*)&xd_bf[(size_t)t0 * 128 + c4];
        a0 += bf2f(b.x); a1 += bf2f(b.y); a2 += bf2f(b.z); a3 += bf2f(b.w); }
      if (t1 < k) { ushort4 b = *(const ushort4*)&xd_bf[(size_t)t1 * 128 + c4];
        a0 += bf2f(b.x); a1 += bf2f(b.y); a2 += bf2f(b.z); a3 += bf2f(b.w); }
      if (t2 < k) { ushort4 b = *(const ushort4*)&xd_bf[(size_t)t2 * 128 + c4];
        a0 += bf2f(b.x); a1 += bf2f(b.y); a2 += bf2f(b.z); a3 += bf2f(b.w); }
      if (t3 < k) { ushort4 b = *(const ushort4*)&xd_bf[(size_t)t3 * 128 + c4];
        a0 += bf2f(b.x); a1 += bf2f(b.y); a2 += bf2f(b.z); a3 += bf2f(b.w); }
    }
  }
  for (; j < hi; ++j) {
    int u = idx[j];
    if (!hiHalf) {
      ushort4 b = *(const ushort4*)&res_bf[(size_t)u * 128 + c4];
      a0 += bf2f(b.x); a1 += bf2f(b.y); a2 += bf2f(b.z); a3 += bf2f(b.w);
    } else {
      int tt = nmapL[u];
      if (tt < k) {
        ushort4 b = *(const ushort4*)&xd_bf[(size_t)tt * 128 + c4];
        a0 += bf2f(b.x); a1 += bf2f(b.y); a2 += bf2f(b.z); a3 += bf2f(b.w);
      }
    }
  }
  size_t base = (size_t)v * 256 + (hiHalf ? 128 : 0) + c4;
  *(ushort4*)&agg[base] = make_ushort4(f2bf(a0), f2bf(a1), f2bf(a2), f2bf(a3));
}

// ---- down-path f32 GEMM (CIN=128), 32-row tile ----
template <bool GELU>
__global__ __launch_bounds__(256) void gemm_kernel(const float* __restrict__ A,
                                                   const float* __restrict__ W,
                                                   const float* __restrict__ bias,
                                                   float* __restrict__ out, int n) {
  __shared__ float As[32 * 32];
  __shared__ float Ws[32 * 128];
  int t = threadIdx.x;
  int row0 = blockIdx.x * 32;
  int colg = (t & 31) << 2;
  int rowg = (t >> 5) << 2;
  float acc[4][4];
#pragma unroll
  for (int i = 0; i < 4; ++i)
#pragma unroll
    for (int j = 0; j < 4; ++j) acc[i][j] = 0.f;

  for (int k0 = 0; k0 < 128; k0 += 32) {
    __syncthreads();
    {
      int ar = t >> 3, ac = (t & 7) << 2;
      float4 av = make_float4(0.f, 0.f, 0.f, 0.f);
      if (row0 + ar < n) av = *(const float4*)&A[(size_t)(row0 + ar) * 128 + k0 + ac];
      *(float4*)&As[ar * 32 + ac] = av;
    }
#pragma unroll
    for (int l = 0; l < 4; ++l) {
      int id = t + l * 256;
      int kk = id >> 5, wc = (id & 31) << 2;
      *(float4*)&Ws[kk * 128 + wc] = *(const float4*)&W[(size_t)(k0 + kk) * 128 + wc];
    }
    __syncthreads();
#pragma unroll
    for (int kk = 0; kk < 32; kk += 4) {
      float4 wv[4];
#pragma unroll
      for (int j = 0; j < 4; ++j) wv[j] = *(const float4*)&Ws[(kk + j) * 128 + colg];
#pragma unroll
      for (int i = 0; i < 4; ++i) {
        float4 av = *(const float4*)&As[(rowg + i) * 32 + kk];
        acc[i][0] += av.x * wv[0].x + av.y * wv[1].x + av.z * wv[2].x + av.w * wv[3].x;
        acc[i][1] += av.x * wv[0].y + av.y * wv[1].y + av.z * wv[2].y + av.w * wv[3].y;
        acc[i][2] += av.x * wv[0].z + av.y * wv[1].z + av.z * wv[2].z + av.w * wv[3].z;
        acc[i][3] += av.x * wv[0].w + av.y * wv[1].w + av.z * wv[2].w + av.w * wv[3].w;
      }
    }
  }
  float4 bv = *(const float4*)&bias[colg];
#pragma unroll
  for (int i = 0; i < 4; ++i) {
    int rr = row0 + rowg + i;
    if (rr < n) {
      float4 o = make_float4(acc[i][0] + bv.x, acc[i][1] + bv.y, acc[i][2] + bv.z, acc[i][3] + bv.w);
      if (GELU) { o.x = gelu_f(o.x); o.y = gelu_f(o.y); o.z = gelu_f(o.z); o.w = gelu_f(o.w); }
      *(float4*)&out[(size_t)rr * 128 + colg] = o;
    }
  }
}

// ---- up-path MFMA GEMM (gelu, bf16 out) ----
template <int K>
__global__ __launch_bounds__(256) void gemm_mfma_kernel(const u16* __restrict__ A,
                                                        const u16* __restrict__ WT,
                                                        const float* __restrict__ bias,
                                                        u16* __restrict__ out, int n) {
  __shared__ u16 As[64 * 72];
  __shared__ u16 Ws[128 * 72];
  int t = threadIdx.x;
  int lane = t & 63, wave = t >> 6;
  int row0 = blockIdx.x * 64;
  f32x4 acc[8];
#pragma unroll
  for (int i = 0; i < 8; ++i) acc[i] = (f32x4){0.f, 0.f, 0.f, 0.f};

  for (int k0 = 0; k0 < K; k0 += 64) {
    __syncthreads();
#pragma unroll
    for (int i = 0; i < 2; ++i) {
      int c = t + i * 256;
      int r = c >> 3, seg = c & 7;
      bf16x8 v = {0, 0, 0, 0, 0, 0, 0, 0};
      if (row0 + r < n) v = *(const bf16x8*)&A[(size_t)(row0 + r) * K + k0 + seg * 8];
      *(bf16x8*)&As[r * 72 + seg * 8] = v;
    }
#pragma unroll
    for (int i = 0; i < 4; ++i) {
      int c = t + i * 256;
      int r = c >> 3, seg = c & 7;
      *(bf16x8*)&Ws[r * 72 + seg * 8] = *(const bf16x8*)&WT[(size_t)r * K + k0 + seg * 8];
    }
    __syncthreads();
#pragma unroll
    for (int kk = 0; kk < 64; kk += 32) {
      bf16x8 a = *(const bf16x8*)&As[(wave * 16 + (lane & 15)) * 72 + kk + (lane >> 4) * 8];
#pragma unroll
      for (int ct = 0; ct < 8; ++ct) {
        bf16x8 b = *(const bf16x8*)&Ws[(ct * 16 + (lane & 15)) * 72 + kk + (lane >> 4) * 8];
        acc[ct] = __builtin_amdgcn_mfma_f32_16x16x32_bf16(a, b, acc[ct], 0, 0, 0);
      }
    }
  }
  int colb = lane & 15, rquad = lane >> 4;
#pragma unroll
  for (int ct = 0; ct < 8; ++ct) {
#pragma unroll
    for (int r = 0; r < 4; ++r) {
      int row = row0 + wave * 16 + rquad * 4 + r;
      if (row < n) {
        int col = ct * 16 + colb;
        out[(size_t)row * 128 + col] = f2bf(gelu_f(acc[ct][r] + bias[col]));
      }
    }
  }
}

// ---- up-path MFMA GEMM3 + fused LayerNorm ----
template <bool WF32, bool WBF>
__global__ __launch_bounds__(256) void gemm_mfma_ln_kernel(
    const u16* __restrict__ A, const u16* __restrict__ WT, const float* __restrict__ bias,
    const float* __restrict__ g, const float* __restrict__ beta,
    float* __restrict__ out, u16* __restrict__ outbf, int n) {
  __shared__ u16 As[64 * 72];
  __shared__ u16 Ws[128 * 72];
  int t = threadIdx.x;
  int lane = t & 63, wave = t >> 6;
  int row0 = blockIdx.x * 64;
  f32x4 acc[8];
#pragma unroll
  for (int i = 0; i < 8; ++i) acc[i] = (f32x4){0.f, 0.f, 0.f, 0.f};

  for (int k0 = 0; k0 < 128; k0 += 64) {
    __syncthreads();
#pragma unroll
    for (int i = 0; i < 2; ++i) {
      int c = t + i * 256;
      int r = c >> 3, seg = c & 7;
      bf16x8 v = {0, 0, 0, 0, 0, 0, 0, 0};
      if (row0 + r < n) v = *(const bf16x8*)&A[(size_t)(row0 + r) * 128 + k0 + seg * 8];
      *(bf16x8*)&As[r * 72 + seg * 8] = v;
    }
#pragma unroll
    for (int i = 0; i < 4; ++i) {
      int c = t + i * 256;
      int r = c >> 3, seg = c & 7;
      *(bf16x8*)&Ws[r * 72 + seg * 8] = *(const bf16x8*)&WT[(size_t)r * 128 + k0 + seg * 8];
    }
    __syncthreads();
#pragma unroll
    for (int kk = 0; kk < 64; kk += 32) {
      bf16x8 a = *(const bf16x8*)&As[(wave * 16 + (lane & 15)) * 72 + kk + (lane >> 4) * 8];
#pragma unroll
      for (int ct = 0; ct < 8; ++ct) {
        bf16x8 b = *(const bf16x8*)&Ws[(ct * 16 + (lane & 15)) * 72 + kk + (lane >> 4) * 8];
        acc[ct] = __builtin_amdgcn_mfma_f32_16x16x32_bf16(a, b, acc[ct], 0, 0, 0);
      }
    }
  }
  int colb = lane & 15, rquad = lane >> 4;
  float bv[8], gv[8], bev[8];
#pragma unroll
  for (int ct = 0; ct < 8; ++ct) {
    int col = ct * 16 + colb;
    bv[ct] = bias[col]; gv[ct] = g[col]; bev[ct] = beta[col];
  }
#pragma unroll
  for (int r = 0; r < 4; ++r) {
    float s1 = 0.f;
#pragma unroll
    for (int ct = 0; ct < 8; ++ct) s1 += acc[ct][r] + bv[ct];
#pragma unroll
    for (int o = 1; o <= 8; o <<= 1) s1 += __shfl_xor(s1, o, 64);
    float mu = s1 * (1.0f / 128.0f);
    float s2 = 0.f;
#pragma unroll
    for (int ct = 0; ct < 8; ++ct) { float d = acc[ct][r] + bv[ct] - mu; s2 += d * d; }
#pragma unroll
    for (int o = 1; o <= 8; o <<= 1) s2 += __shfl_xor(s2, o, 64);
    float rs = rsqrtf(s2 * (1.0f / 128.0f) + 1e-5f);
    int row = row0 + wave * 16 + rquad * 4 + r;
    if (row < n) {
#pragma unroll
      for (int ct = 0; ct < 8; ++ct) {
        int col = ct * 16 + colb;
        float o = gv[ct] * (acc[ct][r] + bv[ct] - mu) * rs + bev[ct];
        if (WF32) out[(size_t)row * 128 + col] = o;
        if (WBF)  outbf[(size_t)row * 128 + col] = f2bf(o);
      }
    }
  }
}

// fused convert+transpose of all 9 up-path weights, one dispatch
__global__ void wconv_all_kernel(const float* __restrict__ uW1, const float* __restrict__ uW2,
                                 const float* __restrict__ uW3, u16* __restrict__ wt1,
                                 u16* __restrict__ wt2, u16* __restrict__ wt3) {
  int i = blockIdx.x * 256 + threadIdx.x;
  if (i >= 3 * 65536) return;
  int lvl = i >> 16, rem = i & 65535;
  if (rem < 32768) {  // W1: [256][128] -> [128][256]
    int k = rem >> 7, c = rem & 127;
    wt1[(size_t)lvl * 32768 + c * 256 + k] = f2bf(uW1[(size_t)lvl * 32768 + rem]);
  } else if (rem < 49152) {
    int j = rem - 32768; int k = j >> 7, c = j & 127;
    wt2[(size_t)lvl * 16384 + c * 128 + k] = f2bf(uW2[(size_t)lvl * 16384 + j]);
  } else {
    int j = rem - 49152; int k = j >> 7, c = j & 127;
    wt3[(size_t)lvl * 16384 + c * 128 + k] = f2bf(uW3[(size_t)lvl * 16384 + j]);
  }
}

// ---- down-path LN (+ optional bf16 copy, + optional fused next-level score) ----
// Score path is bit-identical to score_kernel's reduction tree.
template <bool SCORE, bool WBF>
__global__ void ln_kernel(const float* __restrict__ h, const float* __restrict__ g,
                          const float* __restrict__ beta, float* __restrict__ out,
                          u16* __restrict__ outbf, const float* __restrict__ wnext,
                          const double* __restrict__ sqn, float* __restrict__ key,
                          float* __restrict__ valt, int n) {
  int wave = threadIdx.x >> 6, lane = threadIdx.x & 63;
  int i = blockIdx.x * 4 + wave;
  if (i >= n) return;
  float2 hv = *(const float2*)&h[(size_t)i * 128 + lane * 2];
  float s = hv.x + hv.y;
  for (int o = 32; o; o >>= 1) s += __shfl_down(s, o, 64);
  float mu = __shfl(s, 0, 64) * (1.0f / 128.0f);
  float dx = hv.x - mu, dy = hv.y - mu;
  float q = dx * dx + dy * dy;
  for (int o = 32; o; o >>= 1) q += __shfl_down(q, o, 64);
  float var = __shfl(q, 0, 64) * (1.0f / 128.0f);
  float rs = rsqrtf(var + 1e-5f);
  float2 gv = *(const float2*)&g[lane * 2];
  float2 bv = *(const float2*)&beta[lane * 2];
  float2 o2; o2.x = gv.x * dx * rs + bv.x; o2.y = gv.y * dy * rs + bv.y;
  *(float2*)&out[(size_t)i * 128 + lane * 2] = o2;
  if (WBF)
    *(ushort2*)&outbf[(size_t)i * 128 + lane * 2] = make_ushort2(f2bf(o2.x), f2bf(o2.y));
  if (SCORE) {
    float2 wv = *(const float2*)&wnext[lane * 2];
    double d = (double)o2.x * wv.x + (double)o2.y * wv.y;
    for (int o = 32; o; o >>= 1) d += __shfl_down(d, o, 64);
    if (lane == 0) {
      key[i]  = (float)d;
      valt[i] = (float)tanh(d / sqn[0]);
    }
  }
}

// ---------------------------------------------------------------------------

static inline int cdiv(int a, int b) { return (a + b - 1) / b; }

extern "C" void kernel_launch(void* const* d_in, const int* in_sizes, int n_in,
                              void* d_out, int out_size, void* d_ws, size_t ws_size,
                              hipStream_t stream) {
  const float* x0   = (const float*)d_in[0];
  const int*   snd  = (const int*)d_in[1];
  const int*   rcv  = (const int*)d_in[2];
  const float* poolw = (const float*)d_in[3];
  const float* dW1 = (const float*)d_in[4];
  const float* db1 = (const float*)d_in[5];
  const float* dW2 = (const float*)d_in[6];
  const float* db2 = (const float*)d_in[7];
  const float* dW3 = (const float*)d_in[8];
  const float* db3 = (const float*)d_in[9];
  const float* dg  = (const float*)d_in[10];
  const float* dbe = (const float*)d_in[11];
  const float* uW1 = (const float*)d_in[12];
  const float* ub1 = (const float*)d_in[13];
  const float* uW2 = (const float*)d_in[14];
  const float* ub2 = (const float*)d_in[15];
  const float* uW3 = (const float*)d_in[16];
  const float* ub3 = (const float*)d_in[17];
  const float* ug  = (const float*)d_in[18];
  const float* ube = (const float*)d_in[19];

  const int N0 = in_sizes[0] / 128;
  const int E  = in_sizes[1];
  const int N1 = (N0 + 1) / 2, N2 = (N1 + 1) / 2, N3 = (N2 + 1) / 2;

  // ---- workspace carve ----
  char* p = (char*)d_ws;
  auto alloc = [&](size_t bytes) -> void* {
    void* r = (void*)p;
    p += (bytes + 255) & ~(size_t)255;
    return r;
  };
  float* key  = (float*)alloc((size_t)N0 * 4);
  float* valt = (float*)alloc((size_t)N0 * 4);
  // hist region: [hi 64K][lo 64K][csum_hi 256][csum_lo 256] — one memset covers all
  int*   hist = (int*)alloc((size_t)(2 * 65536 + 512) * 4);
  int*   csum_hi = hist + 2 * 65536;
  int*   csum_lo = hist + 2 * 65536 + 256;
  int*   meta = (int*)alloc(64 * 4);
  int*   tcnt = (int*)alloc(512 * 4);
  int*   bsum = (int*)alloc(256 * 4);
  unsigned char* selt = (unsigned char*)alloc((size_t)N0);
  int*   nm1 = (int*)alloc((size_t)(N0 + 1) * 4);   // level0 node -> level1 slot (or N1)
  int*   nm2 = (int*)alloc((size_t)(N1 + 1) * 4);
  int*   nm3 = (int*)alloc((size_t)(N2 + 1) * 4);
  int*   perm0 = (int*)alloc((size_t)N1 * 4);
  int*   perm1 = (int*)alloc((size_t)N2 * 4);
  int*   perm2 = (int*)alloc((size_t)N3 * 4);
  float* vals  = (float*)alloc((size_t)N1 * 4);
  double* sqn  = (double*)alloc(8 * 8);
  // edge lists (down only; h2b aliases this region during up)
  int* s1 = (int*)alloc((size_t)E * 4); int* r1 = (int*)alloc((size_t)E * 4);
  int* s2 = (int*)alloc((size_t)E * 4); int* r2 = (int*)alloc((size_t)E * 4);
  int* s3 = (int*)alloc((size_t)E * 4); int* r3 = (int*)alloc((size_t)E * 4);
  float* x1 = (float*)alloc((size_t)N1 * 128 * 4);
  float* x2 = (float*)alloc((size_t)N2 * 128 * 4);
  float* x3 = (float*)alloc((size_t)N3 * 128 * 4);
  float* xp = (float*)alloc((size_t)N1 * 128 * 4);   // down only; h1b aliases in up
  float* aggf = (float*)alloc((size_t)N1 * 128 * 4); // down agg out
  float* h1f  = (float*)alloc((size_t)N1 * 128 * 4); // down mlp scratch
  float* h2f  = (float*)alloc((size_t)N1 * 128 * 4);
  u16* agg_bf = (u16*)alloc((size_t)N0 * 256 * 2);   // up agg out
  u16* res0_bf = (u16*)alloc((size_t)N0 * 128 * 2);  // bf16 copies for fused up agg
  u16* res1_bf = (u16*)alloc((size_t)N1 * 128 * 2);
  u16* res2_bf = (u16*)alloc((size_t)N2 * 128 * 2);
  u16* x3_bf   = (u16*)alloc((size_t)N3 * 128 * 2);
  u16* xu2_bf  = (u16*)alloc((size_t)N2 * 128 * 2);
  u16* xu1_bf  = (u16*)alloc((size_t)N1 * 128 * 2);
  u16* wt1 = (u16*)alloc((size_t)3 * 128 * 256 * 2);
  u16* wt2 = (u16*)alloc((size_t)3 * 128 * 128 * 2);
  u16* wt3 = (u16*)alloc((size_t)3 * 128 * 128 * 2);
  int* off0 = (int*)alloc((size_t)(N0 + 1) * 4); int* cur0 = (int*)alloc((size_t)N0 * 4);
  int* idx0 = (int*)alloc((size_t)2 * E * 4);
  int* off1 = (int*)alloc((size_t)(N1 + 1) * 4); int* cur1 = (int*)alloc((size_t)N1 * 4);
  int* idx1 = (int*)alloc((size_t)2 * E * 4);
  int* off2 = (int*)alloc((size_t)(N2 + 1) * 4); int* cur2 = (int*)alloc((size_t)N2 * 4);
  int* idx2 = (int*)alloc((size_t)2 * E * 4);
  int* off3 = (int*)alloc((size_t)(N3 + 1) * 4); int* cur3 = (int*)alloc((size_t)N3 * 4);
  int* idx3 = (int*)alloc((size_t)2 * E * 4);

  // phase-disjoint aliases (up-phase bf16 activations over dead down buffers)
  u16* h1b = (u16*)xp;              // N0*128*2 over xp
  u16* h2b = (u16*)s1;              // N0*128*2 over s1..r3

  auto run_scan = [&](int* curB, int* offB, int n) {
    int nb = cdiv(n, 256);
    scan_part_kernel<<<nb, 256, 0, stream>>>(curB, bsum, n);
    scan_final_kernel<<<nb, 256, 0, stream>>>(curB, bsum, offB, curB, n);
  };

  auto run_scatter = [&](const int* s, const int* r, int* cur, int* idx, int n) {
    if (n >= 16384) {
      int nb = cdiv(E, 2048);
      int per = cdiv(n, 8);
      int rshift = 0;
      while ((1 << rshift) < per) ++rshift;
      csr_scatter_part_kernel<<<nb * 8, 256, 0, stream>>>(s, r, cur, idx, E, n, rshift);
    } else {
      csr_scatter_kernel<<<cdiv(E, 256), 256, 0, stream>>>(s, r, cur, idx, E, n);
    }
  };

  // ---- one-time converts ----
  wconv_all_kernel<<<cdiv(3 * 65536, 256), 256, 0, stream>>>(uW1, uW2, uW3, wt1, wt2, wt3);
  xconv_kernel<<<cdiv(N0 * 32, 256), 256, 0, stream>>>(x0, res0_bf, N0);
  wnorm_kernel<<<1, 64, 0, stream>>>(poolw, sqn);

  // ---- level-0 CSR (for the final up step) ----
  hipMemsetAsync(cur0, 0, (size_t)N0 * 4, stream);
  deg_kernel<<<cdiv(E, 256), 256, 0, stream>>>(snd, rcv, cur0, E, N0);
  run_scan(cur0, off0, N0);
  run_scatter(snd, rcv, cur0, idx0, N0);

  // ---- generic down step (f32 exact; feeds top-k selection) ----
  // lvl<2: ln also emits next level's key/valt (bit-identical to score_kernel).
  auto down_step = [&](int n, int k, const float* xcur, const int* sin, const int* rin,
                       int* sout, int* rout, int* permL, int* nmL, float* xnext,
                       u16* xnext_bf, int lvl, int* offL, int* curL, int* idxL) {
    int nb = cdiv(n, 256);
    hipMemsetAsync(hist, 0, (size_t)(2 * 65536 + 512) * 4, stream);
    hist_hi_kernel<<<nb, 256, 0, stream>>>(key, hist, csum_hi, n);
    find_hi2_kernel<<<1, 256, 0, stream>>>(hist, csum_hi, meta, k);
    hist_lo_kernel<<<nb, 256, 0, stream>>>(key, meta, hist + 65536, csum_lo, n);
    find_lo2_kernel<<<1, 256, 0, stream>>>(hist + 65536, csum_lo, meta);
    tie_count_kernel<<<nb, 256, 0, stream>>>(key, meta, tcnt, n);
    tie_mark_kernel<<<nb, 256, 0, stream>>>(key, meta, tcnt, selt, n);
    select_kernel<<<cdiv(n + 1, 256), 256, 0, stream>>>(key, valt, selt, meta, permL, vals, nmL, n, k);
    pool_kernel<<<cdiv(k * 32, 256), 256, 0, stream>>>(xcur, permL, vals, xp, k);
    hipMemsetAsync(curL, 0, (size_t)k * 4, stream);
    remap_deg_kernel<<<cdiv(E, 256), 256, 0, stream>>>(sin, rin, nmL, sout, rout, curL, E, k);
    run_scan(curL, offL, k);
    run_scatter(sout, rout, curL, idxL, k);
    agg_kernel<<<cdiv(k, 4), 256, 0, stream>>>(xp, offL, idxL, aggf, k);
    gemm_kernel<true><<<cdiv(k, 32), 256, 0, stream>>>(
        aggf, dW1 + (size_t)lvl * 128 * 128, db1 + (size_t)lvl * 128, h1f, k);
    gemm_kernel<true><<<cdiv(k, 32), 256, 0, stream>>>(
        h1f, dW2 + (size_t)lvl * 128 * 128, db2 + (size_t)lvl * 128, h2f, k);
    gemm_kernel<false><<<cdiv(k, 32), 256, 0, stream>>>(
        h2f, dW3 + (size_t)lvl * 128 * 128, db3 + (size_t)lvl * 128, h1f, k);
    if (lvl < 2)
      ln_kernel<true, true><<<cdiv(k, 4), 256, 0, stream>>>(
          h1f, dg + (size_t)lvl * 128, dbe + (size_t)lvl * 128, xnext, xnext_bf,
          poolw + (size_t)(lvl + 1) * 128, sqn + (lvl + 1), key, valt, k);
    else
      ln_kernel<false, true><<<cdiv(k, 4), 256, 0, stream>>>(
          h1f, dg + (size_t)lvl * 128, dbe + (size_t)lvl * 128, xnext, xnext_bf,
          nullptr, nullptr, nullptr, nullptr, k);
  };

  // level-0 score from x0
  score_kernel<<<cdiv(N0, 4), 256, 0, stream>>>(x0, poolw, key, valt, N0);
  down_step(N0, N1, x0, snd, rcv, s1, r1, perm0, nm1, x1, res1_bf, 0, off1, cur1, idx1);
  down_step(N1, N2, x1, s1, r1, s2, r2, perm1, nm2, x2, res2_bf, 1, off2, cur2, idx2);
  down_step(N2, N3, x2, s2, r2, s3, r3, perm2, nm3, x3, x3_bf, 2, off3, cur3, idx3);

  // ---- generic up step (bf16 path, fused agg + fused LN) ----
  auto up_step = [&](int n, const u16* resb, const u16* xdb, const int* nmL, int kdeep,
                     int lvl, const int* offL, const int* idxL,
                     bool wantF32, float* outF32, u16* outBF) {
    agg_up_kernel<<<cdiv(n, 4), 256, 0, stream>>>(resb, xdb, nmL, offL, idxL, agg_bf, n, kdeep);
    gemm_mfma_kernel<256><<<cdiv(n, 64), 256, 0, stream>>>(
        agg_bf, wt1 + (size_t)lvl * 128 * 256, ub1 + (size_t)lvl * 128, h1b, n);
    gemm_mfma_kernel<128><<<cdiv(n, 64), 256, 0, stream>>>(
        h1b, wt2 + (size_t)lvl * 128 * 128, ub2 + (size_t)lvl * 128, h2b, n);
    if (wantF32)
      gemm_mfma_ln_kernel<true, false><<<cdiv(n, 64), 256, 0, stream>>>(
          h2b, wt3 + (size_t)lvl * 128 * 128, ub3 + (size_t)lvl * 128,
          ug + (size_t)lvl * 128, ube + (size_t)lvl * 128, outF32, nullptr, n);
    else
      gemm_mfma_ln_kernel<false, true><<<cdiv(n, 64), 256, 0, stream>>>(
          h2b, wt3 + (size_t)lvl * 128 * 128, ub3 + (size_t)lvl * 128,
          ug + (size_t)lvl * 128, ube + (size_t)lvl * 128, nullptr, outBF, n);
  };

  up_step(N2, res2_bf, x3_bf,  nm3, N3, 0, off2, idx2, false, nullptr, xu2_bf);
  up_step(N1, res1_bf, xu2_bf, nm2, N2, 1, off1, idx1, false, nullptr, xu1_bf);
  up_step(N0, res0_bf, xu1_bf, nm1, N1, 2, off0, idx0, true, (float*)d_out, nullptr);

  (void)n_in; (void)out_size; (void)ws_size;
}

// Round 7
// 1125.981 us; speedup vs baseline: 1.3092x; 1.3092x over previous
//
#include <hip/hip_runtime.h>
#include <math.h>

// ---------------------------------------------------------------------------
// MeshGraphUnet2 forward on gfx950.  Round 6: fix csum atomic contention
// (LDS-accumulated per-block, flush with few global atomics). Keeps round-5
// fusions: fused up-agg, gemm3+LN, ln+score, 2-pass scan, XCD scatter.
// ---------------------------------------------------------------------------

typedef unsigned short u16;
typedef short bf16x8 __attribute__((ext_vector_type(8)));
typedef float f32x4 __attribute__((ext_vector_type(4)));

__device__ __forceinline__ unsigned int fkey(float f) {
  unsigned int b = __float_as_uint(f);
  return (b & 0x80000000u) ? ~b : (b | 0x80000000u);  // monotonic float->uint
}

__device__ __forceinline__ float gelu_f(float v) {
  return 0.5f * v * (1.0f + erff(v * 0.70710678118654752f));
}

__device__ __forceinline__ u16 f2bf(float f) {
  unsigned u = __float_as_uint(f);
  u = (u + 0x7FFFu + ((u >> 16) & 1u)) >> 16;  // round-nearest-even
  return (u16)u;
}
__device__ __forceinline__ float bf2f(u16 u) {
  return __uint_as_float(((unsigned)u) << 16);
}

// ---- level-0 scoring: key[i] = (float)(x[i,:].w) f64, valt = tanh(d/||w||)
__global__ void score_kernel(const float* __restrict__ x, const float* __restrict__ w,
                             float* __restrict__ key, float* __restrict__ valt, int n) {
  int wave = threadIdx.x >> 6, lane = threadIdx.x & 63;
  int i = blockIdx.x * 4 + wave;
  if (i >= n) return;
  float2 xv = *(const float2*)&x[(size_t)i * 128 + lane * 2];
  float2 wv = *(const float2*)&w[lane * 2];
  double d  = (double)xv.x * wv.x + (double)xv.y * wv.y;
  double nw = (double)wv.x * wv.x + (double)wv.y * wv.y;
  for (int o = 32; o; o >>= 1) { d += __shfl_down(d, o, 64); nw += __shfl_down(nw, o, 64); }
  if (lane == 0) {
    key[i]  = (float)d;
    valt[i] = (float)tanh(d / sqrt(nw));
  }
}

// precompute sqrt(||w||^2) per level with the SAME reduction tree as score_kernel
__global__ void wnorm_kernel(const float* __restrict__ poolw, double* __restrict__ sqn) {
  int lane = threadIdx.x & 63;
  for (int l = 0; l < 3; ++l) {
    float2 wv = *(const float2*)&poolw[l * 128 + lane * 2];
    double nw = (double)wv.x * wv.x + (double)wv.y * wv.y;
    for (int o = 32; o; o >>= 1) nw += __shfl_down(nw, o, 64);
    if (lane == 0) sqn[l] = sqrt(nw);
  }
}

// x0 f32 -> bf16
__global__ void xconv_kernel(const float* __restrict__ x, u16* __restrict__ xb, int n) {
  int gid = blockIdx.x * 256 + threadIdx.x;
  if (gid >= n * 32) return;
  float4 a = *(const float4*)&x[(size_t)gid * 4];
  *(ushort4*)&xb[(size_t)gid * 4] = make_ushort4(f2bf(a.x), f2bf(a.y), f2bf(a.z), f2bf(a.w));
}

// ---- histograms; csum accumulated in LDS per block, flushed with few atomics ----
__global__ void hist_hi_kernel(const float* __restrict__ key, int* __restrict__ hist,
                               int* __restrict__ csum, int n) {
  __shared__ int lc[256];
  lc[threadIdx.x] = 0;
  __syncthreads();
  int i = blockIdx.x * 256 + threadIdx.x;
  if (i < n) {
    unsigned b = fkey(key[i]) >> 16;
    atomicAdd(&hist[b], 1);
    atomicAdd(&lc[b >> 8], 1);
  }
  __syncthreads();
  int v = lc[threadIdx.x];
  if (v) atomicAdd(&csum[threadIdx.x], v);
}

__global__ void hist_lo_kernel(const float* __restrict__ key, const int* __restrict__ meta,
                               int* __restrict__ hist, int* __restrict__ csum, int n) {
  __shared__ int lc[256];
  lc[threadIdx.x] = 0;
  __syncthreads();
  int i = blockIdx.x * 256 + threadIdx.x;
  if (i < n) {
    unsigned u = fkey(key[i]);
    if ((u >> 16) == (unsigned)meta[0]) {
      unsigned b = u & 0xFFFFu;
      atomicAdd(&hist[b], 1);
      atomicAdd(&lc[b >> 8], 1);
    }
  }
  __syncthreads();
  int v = lc[threadIdx.x];
  if (v) atomicAdd(&csum[threadIdx.x], v);
}

__global__ void find_hi2_kernel(const int* __restrict__ hist, const int* __restrict__ csum,
                                int* __restrict__ meta, int k) {
  __shared__ int s[256];
  __shared__ int cSh, cumSh;
  int t = threadIdx.x;
  s[t] = csum[t];
  __syncthreads();
  if (t == 0) {
    int cum = 0, c = 0;
    for (int i = 255; i >= 0; --i) {
      if (cum + s[i] >= k) { c = i; break; }
      cum += s[i];
    }
    cSh = c; cumSh = cum;
  }
  __syncthreads();
  int c = cSh;
  s[t] = hist[c * 256 + t];
  __syncthreads();
  if (t == 0) {
    int cum = cumSh;
    for (int b = 255; b >= 0; --b) {
      int v = s[b];
      if (cum + v >= k) { meta[0] = c * 256 + b; meta[1] = k - cum; break; }
      cum += v;
    }
  }
}

__global__ void find_lo2_kernel(const int* __restrict__ hist, const int* __restrict__ csum,
                                int* __restrict__ meta) {
  __shared__ int s[256];
  __shared__ int cSh, cumSh;
  int t = threadIdx.x;
  int m = meta[1], B = meta[0];
  s[t] = csum[t];
  __syncthreads();
  if (t == 0) {
    int cum = 0, c = 0;
    for (int i = 255; i >= 0; --i) {
      if (cum + s[i] >= m) { c = i; break; }
      cum += s[i];
    }
    cSh = c; cumSh = cum;
  }
  __syncthreads();
  int c = cSh;
  s[t] = hist[c * 256 + t];
  __syncthreads();
  if (t == 0) {
    int cum = cumSh;
    for (int b = 255; b >= 0; --b) {
      int v = s[b];
      if (cum + v >= m) {
        meta[3] = (int)((((unsigned)B) << 16) | (unsigned)(c * 256 + b));
        meta[4] = m - cum;
        break;
      }
      cum += v;
    }
    meta[5] = 0;
  }
}

__global__ void tie_count_kernel(const float* __restrict__ key, const int* __restrict__ meta,
                                 int* __restrict__ tcnt, int n) {
  __shared__ int cnt[4];
  unsigned uT = (unsigned)meta[3];
  int i = blockIdx.x * 256 + threadIdx.x;
  bool tie = (i < n) && (fkey(key[i]) == uT);
  unsigned long long m = __ballot(tie);
  int lane = threadIdx.x & 63, w = threadIdx.x >> 6;
  if (lane == 0) cnt[w] = __popcll(m);
  __syncthreads();
  if (threadIdx.x == 0) tcnt[blockIdx.x] = cnt[0] + cnt[1] + cnt[2] + cnt[3];
}

// tie mark with self-computed block prefix (nb <= 256 guaranteed)
__global__ void tie_mark_kernel(const float* __restrict__ key, const int* __restrict__ meta,
                                const int* __restrict__ tcnt, unsigned char* __restrict__ selt,
                                int n) {
  __shared__ int red[256];
  __shared__ int woff[4];
  int t = threadIdx.x;
  red[t] = (t < (int)blockIdx.x) ? tcnt[t] : 0;
  __syncthreads();
  for (int s = 128; s; s >>= 1) {
    if (t < s) red[t] += red[t + s];
    __syncthreads();
  }
  int blockbase = red[0];
  unsigned uT = (unsigned)meta[3];
  int tsel = meta[4];
  int i = blockIdx.x * 256 + t;
  bool tie = (i < n) && (fkey(key[i]) == uT);
  unsigned long long m = __ballot(tie);
  int lane = t & 63, w = t >> 6;
  if (lane == 0) woff[w] = __popcll(m);
  __syncthreads();
  if (t == 0) {
    int c = 0;
    for (int q = 0; q < 4; ++q) { int v = woff[q]; woff[q] = c; c += v; }
  }
  __syncthreads();
  if (tie) {
    int pre = __popcll(m & ((1ull << lane) - 1ull));
    int rank = blockbase + woff[w] + pre;
    selt[i] = (rank < tsel) ? 1 : 0;
  }
}

__global__ void select_kernel(const float* __restrict__ key, const float* __restrict__ valt,
                              const unsigned char* __restrict__ selt, int* __restrict__ meta,
                              int* __restrict__ perm, float* __restrict__ vals,
                              int* __restrict__ nmap, int n, int k) {
  int i = blockIdx.x * 256 + threadIdx.x;
  if (i > n) return;
  if (i == n) { nmap[n] = k; return; }
  unsigned u  = fkey(key[i]);
  unsigned uT = (unsigned)meta[3];
  bool sel = (u > uT) || (u == uT && selt[i] != 0);
  if (sel) {
    int slot = atomicAdd(&meta[5], 1);
    perm[slot] = i; vals[slot] = valt[i]; nmap[i] = slot;
  } else {
    nmap[i] = k;
  }
}

__global__ void pool_kernel(const float* __restrict__ x, const int* __restrict__ perm,
                            const float* __restrict__ vals, float* __restrict__ xp, int k) {
  int gid = blockIdx.x * 256 + threadIdx.x;
  int t = gid >> 5;
  if (t >= k) return;
  int c = (gid & 31) << 2;
  float v = vals[t];
  float4 a = *(const float4*)&x[(size_t)perm[t] * 128 + c];
  a.x *= v; a.y *= v; a.z *= v; a.w *= v;
  *(float4*)&xp[(size_t)t * 128 + c] = a;
}

// remap + degree count fused (deg zeroed before)
__global__ void remap_deg_kernel(const int* __restrict__ s_in, const int* __restrict__ r_in,
                                 const int* __restrict__ nmap, int* __restrict__ s_out,
                                 int* __restrict__ r_out, int* __restrict__ deg, int E, int k) {
  int e = blockIdx.x * 256 + threadIdx.x;
  if (e >= E) return;
  int a = nmap[s_in[e]], b = nmap[r_in[e]];
  if (a == k || b == k) { a = k; b = k; }
  s_out[e] = a; r_out[e] = b;
  if (a < k) { atomicAdd(&deg[b], 1); atomicAdd(&deg[a], 1); }
}

__global__ void deg_kernel(const int* __restrict__ s, const int* __restrict__ r,
                           int* __restrict__ deg, int E, int n) {
  int e = blockIdx.x * 256 + threadIdx.x;
  if (e >= E) return;
  int ss = s[e];
  if (ss >= n) return;
  int rr = r[e];
  atomicAdd(&deg[rr], 1);
  atomicAdd(&deg[ss], 1);
}

// ---- 2-pass parallel exclusive scan (self-prefix final; nb <= 256) ----
__global__ void scan_part_kernel(const int* __restrict__ deg, int* __restrict__ bsum, int n) {
  __shared__ int l[256];
  int i = blockIdx.x * 256 + threadIdx.x;
  l[threadIdx.x] = (i < n) ? deg[i] : 0;
  __syncthreads();
  for (int s = 128; s; s >>= 1) {
    if (threadIdx.x < s) l[threadIdx.x] += l[threadIdx.x + s];
    __syncthreads();
  }
  if (threadIdx.x == 0) bsum[blockIdx.x] = l[0];
}

__global__ void scan_final_kernel(const int* __restrict__ deg, const int* __restrict__ bsum,
                                  int* __restrict__ off, int* __restrict__ cur, int n) {
  __shared__ int red[256];
  __shared__ int l[256];
  int i = blockIdx.x * 256 + threadIdx.x;
  int t = threadIdx.x;
  red[t] = (t < (int)blockIdx.x) ? bsum[t] : 0;
  __syncthreads();
  for (int s = 128; s; s >>= 1) {
    if (t < s) red[t] += red[t + s];
    __syncthreads();
  }
  int base = red[0];
  int v = (i < n) ? deg[i] : 0;
  l[t] = v;
  __syncthreads();
#pragma unroll
  for (int s = 1; s < 256; s <<= 1) {
    int add = (t >= s) ? l[t - s] : 0;
    __syncthreads();
    l[t] += add;
    __syncthreads();
  }
  int incl = l[t];
  if (i < n) {
    int e = base + incl - v;
    off[i] = e; cur[i] = e;
    if (i == n - 1) off[n] = base + incl;
  }
}

__global__ void csr_scatter_kernel(const int* __restrict__ s, const int* __restrict__ r,
                                   int* __restrict__ cur, int* __restrict__ idx, int E, int n) {
  int e = blockIdx.x * 256 + threadIdx.x;
  if (e >= E) return;
  int ss = s[e];
  if (ss >= n) return;
  int rr = r[e];
  idx[atomicAdd(&cur[rr], 1)] = ss;
  idx[atomicAdd(&cur[ss], 1)] = rr;
}

// XCD-partitioned scatter (8 node-range groups, group = blockIdx&7)
__global__ void csr_scatter_part_kernel(const int* __restrict__ s, const int* __restrict__ r,
                                        int* __restrict__ cur, int* __restrict__ idx,
                                        int E, int n, int rshift) {
  int g = blockIdx.x & 7;
  int nb = gridDim.x >> 3;
  int bb = blockIdx.x >> 3;
  int lo = g << rshift, hi = (g + 1) << rshift;
  int stride = nb * 256;
  for (int e = bb * 256 + threadIdx.x; e < E; e += stride) {
    int ss = s[e];
    if (ss >= n) continue;
    int rr = r[e];
    if (rr >= lo && rr < hi) idx[atomicAdd(&cur[rr], 1)] = ss;
    if (ss >= lo && ss < hi) idx[atomicAdd(&cur[ss], 1)] = rr;
  }
}

// ---- down-path f32 aggregation (C=128) ----
__global__ void agg_kernel(const float* __restrict__ x, const int* __restrict__ off,
                           const int* __restrict__ idx, float* __restrict__ agg, int n) {
  int wave = threadIdx.x >> 6, lane = threadIdx.x & 63;
  int v = blockIdx.x * 4 + wave;
  if (v >= n) return;
  int lo = off[v], hi = off[v + 1];
  int c = lane * 2;
  float ax = 0.f, ay = 0.f;
  int j = lo;
  for (; j + 4 <= hi; j += 4) {
    int u0 = idx[j], u1 = idx[j + 1], u2 = idx[j + 2], u3 = idx[j + 3];
    float2 a0 = *(const float2*)&x[(size_t)u0 * 128 + c];
    float2 a1 = *(const float2*)&x[(size_t)u1 * 128 + c];
    float2 a2 = *(const float2*)&x[(size_t)u2 * 128 + c];
    float2 a3 = *(const float2*)&x[(size_t)u3 * 128 + c];
    ax += a0.x + a1.x + a2.x + a3.x;
    ay += a0.y + a1.y + a2.y + a3.y;
  }
  for (; j < hi; ++j) {
    int u = idx[j];
    float2 a = *(const float2*)&x[(size_t)u * 128 + c];
    ax += a.x; ay += a.y;
  }
  float2 o; o.x = ax; o.y = ay;
  *(float2*)&agg[(size_t)v * 128 + c] = o;
}

// ---- fused up-path aggregation: agg[v] = [ sum res_bf[u] | sum up(u) ] ----
// up(u) = xd_bf[nmap[u]] if selected else 0. Lanes 0-31 res half, 32-63 up half.
__global__ void agg_up_kernel(const u16* __restrict__ res_bf, const u16* __restrict__ xd_bf,
                              const int* __restrict__ nmapL, const int* __restrict__ off,
                              const int* __restrict__ idx, u16* __restrict__ agg, int n, int k) {
  int wave = threadIdx.x >> 6, lane = threadIdx.x & 63;
  int v = blockIdx.x * 4 + wave;
  if (v >= n) return;
  int lo = off[v], hi = off[v + 1];
  bool hiHalf = lane >= 32;
  int c4 = (lane & 31) << 2;
  float a0 = 0.f, a1 = 0.f, a2 = 0.f, a3 = 0.f;
  int j = lo;
  for (; j + 4 <= hi; j += 4) {
    int u0 = idx[j], u1 = idx[j + 1], u2 = idx[j + 2], u3 = idx[j + 3];
    if (!hiHalf) {
      ushort4 b0 = *(const ushort4*)&res_bf[(size_t)u0 * 128 + c4];
      ushort4 b1 = *(const ushort4*)&res_bf[(size_t)u1 * 128 + c4];
      ushort4 b2 = *(const ushort4*)&res_bf[(size_t)u2 * 128 + c4];
      ushort4 b3 = *(const ushort4*)&res_bf[(size_t)u3 * 128 + c4];
      a0 += bf2f(b0.x) + bf2f(b1.x) + bf2f(b2.x) + bf2f(b3.x);
      a1 += bf2f(b0.y) + bf2f(b1.y) + bf2f(b2.y) + bf2f(b3.y);
      a2 += bf2f(b0.z) + bf2f(b1.z) + bf2f(b2.z) + bf2f(b3.z);
      a3 += bf2f(b0.w) + bf2f(b1.w) + bf2f(b2.w) + bf2f(b3.w);
    } else {
      int t0 = nmapL[u0], t1 = nmapL[u1], t2 = nmapL[u2], t3 = nmapL[u3];
      if (t0 < k) { ushort4 b = *(const ushort4*)&xd_bf[(size_t)t0 * 128 + c4];
        a0 += bf2f(b.x); a1 += bf2f(b.y); a2 += bf2f(b.z); a3 += bf2f(b.w); }
      if (t1 < k) { ushort4 b = *(const ushort4*)&xd_bf[(size_t)t1 * 128 + c4];
        a0 += bf2f(b.x); a1 += bf2f(b.y); a2 += bf2f(b.z); a3 += bf2f(b.w); }
      if (t2 < k) { ushort4 b = *(const ushort4*)&xd_bf[(size_t)t2 * 128 + c4];
        a0 += bf2f(b.x); a1 += bf2f(b.y); a2 += bf2f(b.z); a3 += bf2f(b.w); }
      if (t3 < k) { ushort4 b = *(const ushort4*)&xd_bf[(size_t)t3 * 128 + c4];
        a0 += bf2f(b.x); a1 += bf2f(b.y); a2 += bf2f(b.z); a3 += bf2f(b.w); }
    }
  }
  for (; j < hi; ++j) {
    int u = idx[j];
    if (!hiHalf) {
      ushort4 b = *(const ushort4*)&res_bf[(size_t)u * 128 + c4];
      a0 += bf2f(b.x); a1 += bf2f(b.y); a2 += bf2f(b.z); a3 += bf2f(b.w);
    } else {
      int tt = nmapL[u];
      if (tt < k) {
        ushort4 b = *(const ushort4*)&xd_bf[(size_t)tt * 128 + c4];
        a0 += bf2f(b.x); a1 += bf2f(b.y); a2 += bf2f(b.z); a3 += bf2f(b.w);
      }
    }
  }
  size_t base = (size_t)v * 256 + (hiHalf ? 128 : 0) + c4;
  *(ushort4*)&agg[base] = make_ushort4(f2bf(a0), f2bf(a1), f2bf(a2), f2bf(a3));
}

// ---- down-path f32 GEMM (CIN=128), 32-row tile ----
template <bool GELU>
__global__ __launch_bounds__(256) void gemm_kernel(const float* __restrict__ A,
                                                   const float* __restrict__ W,
                                                   const float* __restrict__ bias,
                                                   float* __restrict__ out, int n) {
  __shared__ float As[32 * 32];
  __shared__ float Ws[32 * 128];
  int t = threadIdx.x;
  int row0 = blockIdx.x * 32;
  int colg = (t & 31) << 2;
  int rowg = (t >> 5) << 2;
  float acc[4][4];
#pragma unroll
  for (int i = 0; i < 4; ++i)
#pragma unroll
    for (int j = 0; j < 4; ++j) acc[i][j] = 0.f;

  for (int k0 = 0; k0 < 128; k0 += 32) {
    __syncthreads();
    {
      int ar = t >> 3, ac = (t & 7) << 2;
      float4 av = make_float4(0.f, 0.f, 0.f, 0.f);
      if (row0 + ar < n) av = *(const float4*)&A[(size_t)(row0 + ar) * 128 + k0 + ac];
      *(float4*)&As[ar * 32 + ac] = av;
    }
#pragma unroll
    for (int l = 0; l < 4; ++l) {
      int id = t + l * 256;
      int kk = id >> 5, wc = (id & 31) << 2;
      *(float4*)&Ws[kk * 128 + wc] = *(const float4*)&W[(size_t)(k0 + kk) * 128 + wc];
    }
    __syncthreads();
#pragma unroll
    for (int kk = 0; kk < 32; kk += 4) {
      float4 wv[4];
#pragma unroll
      for (int j = 0; j < 4; ++j) wv[j] = *(const float4*)&Ws[(kk + j) * 128 + colg];
#pragma unroll
      for (int i = 0; i < 4; ++i) {
        float4 av = *(const float4*)&As[(rowg + i) * 32 + kk];
        acc[i][0] += av.x * wv[0].x + av.y * wv[1].x + av.z * wv[2].x + av.w * wv[3].x;
        acc[i][1] += av.x * wv[0].y + av.y * wv[1].y + av.z * wv[2].y + av.w * wv[3].y;
        acc[i][2] += av.x * wv[0].z + av.y * wv[1].z + av.z * wv[2].z + av.w * wv[3].z;
        acc[i][3] += av.x * wv[0].w + av.y * wv[1].w + av.z * wv[2].w + av.w * wv[3].w;
      }
    }
  }
  float4 bv = *(const float4*)&bias[colg];
#pragma unroll
  for (int i = 0; i < 4; ++i) {
    int rr = row0 + rowg + i;
    if (rr < n) {
      float4 o = make_float4(acc[i][0] + bv.x, acc[i][1] + bv.y, acc[i][2] + bv.z, acc[i][3] + bv.w);
      if (GELU) { o.x = gelu_f(o.x); o.y = gelu_f(o.y); o.z = gelu_f(o.z); o.w = gelu_f(o.w); }
      *(float4*)&out[(size_t)rr * 128 + colg] = o;
    }
  }
}

// ---- up-path MFMA GEMM (gelu, bf16 out) ----
template <int K>
__global__ __launch_bounds__(256) void gemm_mfma_kernel(const u16* __restrict__ A,
                                                        const u16* __restrict__ WT,
                                                        const float* __restrict__ bias,
                                                        u16* __restrict__ out, int n) {
  __shared__ u16 As[64 * 72];
  __shared__ u16 Ws[128 * 72];
  int t = threadIdx.x;
  int lane = t & 63, wave = t >> 6;
  int row0 = blockIdx.x * 64;
  f32x4 acc[8];
#pragma unroll
  for (int i = 0; i < 8; ++i) acc[i] = (f32x4){0.f, 0.f, 0.f, 0.f};

  for (int k0 = 0; k0 < K; k0 += 64) {
    __syncthreads();
#pragma unroll
    for (int i = 0; i < 2; ++i) {
      int c = t + i * 256;
      int r = c >> 3, seg = c & 7;
      bf16x8 v = {0, 0, 0, 0, 0, 0, 0, 0};
      if (row0 + r < n) v = *(const bf16x8*)&A[(size_t)(row0 + r) * K + k0 + seg * 8];
      *(bf16x8*)&As[r * 72 + seg * 8] = v;
    }
#pragma unroll
    for (int i = 0; i < 4; ++i) {
      int c = t + i * 256;
      int r = c >> 3, seg = c & 7;
      *(bf16x8*)&Ws[r * 72 + seg * 8] = *(const bf16x8*)&WT[(size_t)r * K + k0 + seg * 8];
    }
    __syncthreads();
#pragma unroll
    for (int kk = 0; kk < 64; kk += 32) {
      bf16x8 a = *(const bf16x8*)&As[(wave * 16 + (lane & 15)) * 72 + kk + (lane >> 4) * 8];
#pragma unroll
      for (int ct = 0; ct < 8; ++ct) {
        bf16x8 b = *(const bf16x8*)&Ws[(ct * 16 + (lane & 15)) * 72 + kk + (lane >> 4) * 8];
        acc[ct] = __builtin_amdgcn_mfma_f32_16x16x32_bf16(a, b, acc[ct], 0, 0, 0);
      }
    }
  }
  int colb = lane & 15, rquad = lane >> 4;
#pragma unroll
  for (int ct = 0; ct < 8; ++ct) {
#pragma unroll
    for (int r = 0; r < 4; ++r) {
      int row = row0 + wave * 16 + rquad * 4 + r;
      if (row < n) {
        int col = ct * 16 + colb;
        out[(size_t)row * 128 + col] = f2bf(gelu_f(acc[ct][r] + bias[col]));
      }
    }
  }
}

// ---- up-path MFMA GEMM3 + fused LayerNorm ----
template <bool WF32, bool WBF>
__global__ __launch_bounds__(256) void gemm_mfma_ln_kernel(
    const u16* __restrict__ A, const u16* __restrict__ WT, const float* __restrict__ bias,
    const float* __restrict__ g, const float* __restrict__ beta,
    float* __restrict__ out, u16* __restrict__ outbf, int n) {
  __shared__ u16 As[64 * 72];
  __shared__ u16 Ws[128 * 72];
  int t = threadIdx.x;
  int lane = t & 63, wave = t >> 6;
  int row0 = blockIdx.x * 64;
  f32x4 acc[8];
#pragma unroll
  for (int i = 0; i < 8; ++i) acc[i] = (f32x4){0.f, 0.f, 0.f, 0.f};

  for (int k0 = 0; k0 < 128; k0 += 64) {
    __syncthreads();
#pragma unroll
    for (int i = 0; i < 2; ++i) {
      int c = t + i * 256;
      int r = c >> 3, seg = c & 7;
      bf16x8 v = {0, 0, 0, 0, 0, 0, 0, 0};
      if (row0 + r < n) v = *(const bf16x8*)&A[(size_t)(row0 + r) * 128 + k0 + seg * 8];
      *(bf16x8*)&As[r * 72 + seg * 8] = v;
    }
#pragma unroll
    for (int i = 0; i < 4; ++i) {
      int c = t + i * 256;
      int r = c >> 3, seg = c & 7;
      *(bf16x8*)&Ws[r * 72 + seg * 8] = *(const bf16x8*)&WT[(size_t)r * 128 + k0 + seg * 8];
    }
    __syncthreads();
#pragma unroll
    for (int kk = 0; kk < 64; kk += 32) {
      bf16x8 a = *(const bf16x8*)&As[(wave * 16 + (lane & 15)) * 72 + kk + (lane >> 4) * 8];
#pragma unroll
      for (int ct = 0; ct < 8; ++ct) {
        bf16x8 b = *(const bf16x8*)&Ws[(ct * 16 + (lane & 15)) * 72 + kk + (lane >> 4) * 8];
        acc[ct] = __builtin_amdgcn_mfma_f32_16x16x32_bf16(a, b, acc[ct], 0, 0, 0);
      }
    }
  }
  int colb = lane & 15, rquad = lane >> 4;
  float bv[8], gv[8], bev[8];
#pragma unroll
  for (int ct = 0; ct < 8; ++ct) {
    int col = ct * 16 + colb;
    bv[ct] = bias[col]; gv[ct] = g[col]; bev[ct] = beta[col];
  }
#pragma unroll
  for (int r = 0; r < 4; ++r) {
    float s1 = 0.f;
#pragma unroll
    for (int ct = 0; ct < 8; ++ct) s1 += acc[ct][r] + bv[ct];
#pragma unroll
    for (int o = 1; o <= 8; o <<= 1) s1 += __shfl_xor(s1, o, 64);
    float mu = s1 * (1.0f / 128.0f);
    float s2 = 0.f;
#pragma unroll
    for (int ct = 0; ct < 8; ++ct) { float d = acc[ct][r] + bv[ct] - mu; s2 += d * d; }
#pragma unroll
    for (int o = 1; o <= 8; o <<= 1) s2 += __shfl_xor(s2, o, 64);
    float rs = rsqrtf(s2 * (1.0f / 128.0f) + 1e-5f);
    int row = row0 + wave * 16 + rquad * 4 + r;
    if (row < n) {
#pragma unroll
      for (int ct = 0; ct < 8; ++ct) {
        int col = ct * 16 + colb;
        float o = gv[ct] * (acc[ct][r] + bv[ct] - mu) * rs + bev[ct];
        if (WF32) out[(size_t)row * 128 + col] = o;
        if (WBF)  outbf[(size_t)row * 128 + col] = f2bf(o);
      }
    }
  }
}

// fused convert+transpose of all 9 up-path weights, one dispatch
__global__ void wconv_all_kernel(const float* __restrict__ uW1, const float* __restrict__ uW2,
                                 const float* __restrict__ uW3, u16* __restrict__ wt1,
                                 u16* __restrict__ wt2, u16* __restrict__ wt3) {
  int i = blockIdx.x * 256 + threadIdx.x;
  if (i >= 3 * 65536) return;
  int lvl = i >> 16, rem = i & 65535;
  if (rem < 32768) {  // W1: [256][128] -> [128][256]
    int k = rem >> 7, c = rem & 127;
    wt1[(size_t)lvl * 32768 + c * 256 + k] = f2bf(uW1[(size_t)lvl * 32768 + rem]);
  } else if (rem < 49152) {
    int j = rem - 32768; int k = j >> 7, c = j & 127;
    wt2[(size_t)lvl * 16384 + c * 128 + k] = f2bf(uW2[(size_t)lvl * 16384 + j]);
  } else {
    int j = rem - 49152; int k = j >> 7, c = j & 127;
    wt3[(size_t)lvl * 16384 + c * 128 + k] = f2bf(uW3[(size_t)lvl * 16384 + j]);
  }
}

// ---- down-path LN (+ optional bf16 copy, + optional fused next-level score) ----
// Score path is bit-identical to score_kernel's reduction tree.
template <bool SCORE, bool WBF>
__global__ void ln_kernel(const float* __restrict__ h, const float* __restrict__ g,
                          const float* __restrict__ beta, float* __restrict__ out,
                          u16* __restrict__ outbf, const float* __restrict__ wnext,
                          const double* __restrict__ sqn, float* __restrict__ key,
                          float* __restrict__ valt, int n) {
  int wave = threadIdx.x >> 6, lane = threadIdx.x & 63;
  int i = blockIdx.x * 4 + wave;
  if (i >= n) return;
  float2 hv = *(const float2*)&h[(size_t)i * 128 + lane * 2];
  float s = hv.x + hv.y;
  for (int o = 32; o; o >>= 1) s += __shfl_down(s, o, 64);
  float mu = __shfl(s, 0, 64) * (1.0f / 128.0f);
  float dx = hv.x - mu, dy = hv.y - mu;
  float q = dx * dx + dy * dy;
  for (int o = 32; o; o >>= 1) q += __shfl_down(q, o, 64);
  float var = __shfl(q, 0, 64) * (1.0f / 128.0f);
  float rs = rsqrtf(var + 1e-5f);
  float2 gv = *(const float2*)&g[lane * 2];
  float2 bv = *(const float2*)&beta[lane * 2];
  float2 o2; o2.x = gv.x * dx * rs + bv.x; o2.y = gv.y * dy * rs + bv.y;
  *(float2*)&out[(size_t)i * 128 + lane * 2] = o2;
  if (WBF)
    *(ushort2*)&outbf[(size_t)i * 128 + lane * 2] = make_ushort2(f2bf(o2.x), f2bf(o2.y));
  if (SCORE) {
    float2 wv = *(const float2*)&wnext[lane * 2];
    double d = (double)o2.x * wv.x + (double)o2.y * wv.y;
    for (int o = 32; o; o >>= 1) d += __shfl_down(d, o, 64);
    if (lane == 0) {
      key[i]  = (float)d;
      valt[i] = (float)tanh(d / sqn[0]);
    }
  }
}

// ---------------------------------------------------------------------------

static inline int cdiv(int a, int b) { return (a + b - 1) / b; }

extern "C" void kernel_launch(void* const* d_in, const int* in_sizes, int n_in,
                              void* d_out, int out_size, void* d_ws, size_t ws_size,
                              hipStream_t stream) {
  const float* x0   = (const float*)d_in[0];
  const int*   snd  = (const int*)d_in[1];
  const int*   rcv  = (const int*)d_in[2];
  const float* poolw = (const float*)d_in[3];
  const float* dW1 = (const float*)d_in[4];
  const float* db1 = (const float*)d_in[5];
  const float* dW2 = (const float*)d_in[6];
  const float* db2 = (const float*)d_in[7];
  const float* dW3 = (const float*)d_in[8];
  const float* db3 = (const float*)d_in[9];
  const float* dg  = (const float*)d_in[10];
  const float* dbe = (const float*)d_in[11];
  const float* uW1 = (const float*)d_in[12];
  const float* ub1 = (const float*)d_in[13];
  const float* uW2 = (const float*)d_in[14];
  const float* ub2 = (const float*)d_in[15];
  const float* uW3 = (const float*)d_in[16];
  const float* ub3 = (const float*)d_in[17];
  const float* ug  = (const float*)d_in[18];
  const float* ube = (const float*)d_in[19];

  const int N0 = in_sizes[0] / 128;
  const int E  = in_sizes[1];
  const int N1 = (N0 + 1) / 2, N2 = (N1 + 1) / 2, N3 = (N2 + 1) / 2;

  // ---- workspace carve ----
  char* p = (char*)d_ws;
  auto alloc = [&](size_t bytes) -> void* {
    void* r = (void*)p;
    p += (bytes + 255) & ~(size_t)255;
    return r;
  };
  float* key  = (float*)alloc((size_t)N0 * 4);
  float* valt = (float*)alloc((size_t)N0 * 4);
  // hist region: [hi 64K][lo 64K][csum_hi 256][csum_lo 256] — one memset covers all
  int*   hist = (int*)alloc((size_t)(2 * 65536 + 512) * 4);
  int*   csum_hi = hist + 2 * 65536;
  int*   csum_lo = hist + 2 * 65536 + 256;
  int*   meta = (int*)alloc(64 * 4);
  int*   tcnt = (int*)alloc(512 * 4);
  int*   bsum = (int*)alloc(256 * 4);
  unsigned char* selt = (unsigned char*)alloc((size_t)N0);
  int*   nm1 = (int*)alloc((size_t)(N0 + 1) * 4);   // level0 node -> level1 slot (or N1)
  int*   nm2 = (int*)alloc((size_t)(N1 + 1) * 4);
  int*   nm3 = (int*)alloc((size_t)(N2 + 1) * 4);
  int*   perm0 = (int*)alloc((size_t)N1 * 4);
  int*   perm1 = (int*)alloc((size_t)N2 * 4);
  int*   perm2 = (int*)alloc((size_t)N3 * 4);
  float* vals  = (float*)alloc((size_t)N1 * 4);
  double* sqn  = (double*)alloc(8 * 8);
  // edge lists (down only; h2b aliases this region during up)
  int* s1 = (int*)alloc((size_t)E * 4); int* r1 = (int*)alloc((size_t)E * 4);
  int* s2 = (int*)alloc((size_t)E * 4); int* r2 = (int*)alloc((size_t)E * 4);
  int* s3 = (int*)alloc((size_t)E * 4); int* r3 = (int*)alloc((size_t)E * 4);
  float* x1 = (float*)alloc((size_t)N1 * 128 * 4);
  float* x2 = (float*)alloc((size_t)N2 * 128 * 4);
  float* x3 = (float*)alloc((size_t)N3 * 128 * 4);
  float* xp = (float*)alloc((size_t)N1 * 128 * 4);   // down only; h1b aliases in up
  float* aggf = (float*)alloc((size_t)N1 * 128 * 4); // down agg out
  float* h1f  = (float*)alloc((size_t)N1 * 128 * 4); // down mlp scratch
  float* h2f  = (float*)alloc((size_t)N1 * 128 * 4);
  u16* agg_bf = (u16*)alloc((size_t)N0 * 256 * 2);   // up agg out
  u16* res0_bf = (u16*)alloc((size_t)N0 * 128 * 2);  // bf16 copies for fused up agg
  u16* res1_bf = (u16*)alloc((size_t)N1 * 128 * 2);
  u16* res2_bf = (u16*)alloc((size_t)N2 * 128 * 2);
  u16* x3_bf   = (u16*)alloc((size_t)N3 * 128 * 2);
  u16* xu2_bf  = (u16*)alloc((size_t)N2 * 128 * 2);
  u16* xu1_bf  = (u16*)alloc((size_t)N1 * 128 * 2);
  u16* wt1 = (u16*)alloc((size_t)3 * 128 * 256 * 2);
  u16* wt2 = (u16*)alloc((size_t)3 * 128 * 128 * 2);
  u16* wt3 = (u16*)alloc((size_t)3 * 128 * 128 * 2);
  int* off0 = (int*)alloc((size_t)(N0 + 1) * 4); int* cur0 = (int*)alloc((size_t)N0 * 4);
  int* idx0 = (int*)alloc((size_t)2 * E * 4);
  int* off1 = (int*)alloc((size_t)(N1 + 1) * 4); int* cur1 = (int*)alloc((size_t)N1 * 4);
  int* idx1 = (int*)alloc((size_t)2 * E * 4);
  int* off2 = (int*)alloc((size_t)(N2 + 1) * 4); int* cur2 = (int*)alloc((size_t)N2 * 4);
  int* idx2 = (int*)alloc((size_t)2 * E * 4);
  int* off3 = (int*)alloc((size_t)(N3 + 1) * 4); int* cur3 = (int*)alloc((size_t)N3 * 4);
  int* idx3 = (int*)alloc((size_t)2 * E * 4);

  // phase-disjoint aliases (up-phase bf16 activations over dead down buffers)
  u16* h1b = (u16*)xp;              // N0*128*2 over xp
  u16* h2b = (u16*)s1;              // N0*128*2 over s1..r3

  auto run_scan = [&](int* curB, int* offB, int n) {
    int nb = cdiv(n, 256);
    scan_part_kernel<<<nb, 256, 0, stream>>>(curB, bsum, n);
    scan_final_kernel<<<nb, 256, 0, stream>>>(curB, bsum, offB, curB, n);
  };

  auto run_scatter = [&](const int* s, const int* r, int* cur, int* idx, int n) {
    if (n >= 16384) {
      int nb = cdiv(E, 2048);
      int per = cdiv(n, 8);
      int rshift = 0;
      while ((1 << rshift) < per) ++rshift;
      csr_scatter_part_kernel<<<nb * 8, 256, 0, stream>>>(s, r, cur, idx, E, n, rshift);
    } else {
      csr_scatter_kernel<<<cdiv(E, 256), 256, 0, stream>>>(s, r, cur, idx, E, n);
    }
  };

  // ---- one-time converts ----
  wconv_all_kernel<<<cdiv(3 * 65536, 256), 256, 0, stream>>>(uW1, uW2, uW3, wt1, wt2, wt3);
  xconv_kernel<<<cdiv(N0 * 32, 256), 256, 0, stream>>>(x0, res0_bf, N0);
  wnorm_kernel<<<1, 64, 0, stream>>>(poolw, sqn);

  // ---- level-0 CSR (for the final up step) ----
  hipMemsetAsync(cur0, 0, (size_t)N0 * 4, stream);
  deg_kernel<<<cdiv(E, 256), 256, 0, stream>>>(snd, rcv, cur0, E, N0);
  run_scan(cur0, off0, N0);
  run_scatter(snd, rcv, cur0, idx0, N0);

  // ---- generic down step (f32 exact; feeds top-k selection) ----
  auto down_step = [&](int n, int k, const float* xcur, const int* sin, const int* rin,
                       int* sout, int* rout, int* permL, int* nmL, float* xnext,
                       u16* xnext_bf, int lvl, int* offL, int* curL, int* idxL) {
    int nb = cdiv(n, 256);
    hipMemsetAsync(hist, 0, (size_t)(2 * 65536 + 512) * 4, stream);
    hist_hi_kernel<<<nb, 256, 0, stream>>>(key, hist, csum_hi, n);
    find_hi2_kernel<<<1, 256, 0, stream>>>(hist, csum_hi, meta, k);
    hist_lo_kernel<<<nb, 256, 0, stream>>>(key, meta, hist + 65536, csum_lo, n);
    find_lo2_kernel<<<1, 256, 0, stream>>>(hist + 65536, csum_lo, meta);
    tie_count_kernel<<<nb, 256, 0, stream>>>(key, meta, tcnt, n);
    tie_mark_kernel<<<nb, 256, 0, stream>>>(key, meta, tcnt, selt, n);
    select_kernel<<<cdiv(n + 1, 256), 256, 0, stream>>>(key, valt, selt, meta, permL, vals, nmL, n, k);
    pool_kernel<<<cdiv(k * 32, 256), 256, 0, stream>>>(xcur, permL, vals, xp, k);
    hipMemsetAsync(curL, 0, (size_t)k * 4, stream);
    remap_deg_kernel<<<cdiv(E, 256), 256, 0, stream>>>(sin, rin, nmL, sout, rout, curL, E, k);
    run_scan(curL, offL, k);
    run_scatter(sout, rout, curL, idxL, k);
    agg_kernel<<<cdiv(k, 4), 256, 0, stream>>>(xp, offL, idxL, aggf, k);
    gemm_kernel<true><<<cdiv(k, 32), 256, 0, stream>>>(
        aggf, dW1 + (size_t)lvl * 128 * 128, db1 + (size_t)lvl * 128, h1f, k);
    gemm_kernel<true><<<cdiv(k, 32), 256, 0, stream>>>(
        h1f, dW2 + (size_t)lvl * 128 * 128, db2 + (size_t)lvl * 128, h2f, k);
    gemm_kernel<false><<<cdiv(k, 32), 256, 0, stream>>>(
        h2f, dW3 + (size_t)lvl * 128 * 128, db3 + (size_t)lvl * 128, h1f, k);
    if (lvl < 2)
      ln_kernel<true, true><<<cdiv(k, 4), 256, 0, stream>>>(
          h1f, dg + (size_t)lvl * 128, dbe + (size_t)lvl * 128, xnext, xnext_bf,
          poolw + (size_t)(lvl + 1) * 128, sqn + (lvl + 1), key, valt, k);
    else
      ln_kernel<false, true><<<cdiv(k, 4), 256, 0, stream>>>(
          h1f, dg + (size_t)lvl * 128, dbe + (size_t)lvl * 128, xnext, xnext_bf,
          nullptr, nullptr, nullptr, nullptr, k);
  };

  // level-0 score from x0
  score_kernel<<<cdiv(N0, 4), 256, 0, stream>>>(x0, poolw, key, valt, N0);
  down_step(N0, N1, x0, snd, rcv, s1, r1, perm0, nm1, x1, res1_bf, 0, off1, cur1, idx1);
  down_step(N1, N2, x1, s1, r1, s2, r2, perm1, nm2, x2, res2_bf, 1, off2, cur2, idx2);
  down_step(N2, N3, x2, s2, r2, s3, r3, perm2, nm3, x3, x3_bf, 2, off3, cur3, idx3);

  // ---- generic up step (bf16 path, fused agg + fused LN) ----
  auto up_step = [&](int n, const u16* resb, const u16* xdb, const int* nmL, int kdeep,
                     int lvl, const int* offL, const int* idxL,
                     bool wantF32, float* outF32, u16* outBF) {
    agg_up_kernel<<<cdiv(n, 4), 256, 0, stream>>>(resb, xdb, nmL, offL, idxL, agg_bf, n, kdeep);
    gemm_mfma_kernel<256><<<cdiv(n, 64), 256, 0, stream>>>(
        agg_bf, wt1 + (size_t)lvl * 128 * 256, ub1 + (size_t)lvl * 128, h1b, n);
    gemm_mfma_kernel<128><<<cdiv(n, 64), 256, 0, stream>>>(
        h1b, wt2 + (size_t)lvl * 128 * 128, ub2 + (size_t)lvl * 128, h2b, n);
    if (wantF32)
      gemm_mfma_ln_kernel<true, false><<<cdiv(n, 64), 256, 0, stream>>>(
          h2b, wt3 + (size_t)lvl * 128 * 128, ub3 + (size_t)lvl * 128,
          ug + (size_t)lvl * 128, ube + (size_t)lvl * 128, outF32, nullptr, n);
    else
      gemm_mfma_ln_kernel<false, true><<<cdiv(n, 64), 256, 0, stream>>>(
          h2b, wt3 + (size_t)lvl * 128 * 128, ub3 + (size_t)lvl * 128,
          ug + (size_t)lvl * 128, ube + (size_t)lvl * 128, nullptr, outBF, n);
  };

  up_step(N2, res2_bf, x3_bf,  nm3, N3, 0, off2, idx2, false, nullptr, xu2_bf);
  up_step(N1, res1_bf, xu2_bf, nm2, N2, 1, off1, idx1, false, nullptr, xu1_bf);
  up_step(N0, res0_bf, xu1_bf, nm1, N1, 2, off0, idx0, true, (float*)d_out, nullptr);

  (void)n_in; (void)out_size; (void)ws_size;
}

// Round 8
// 1011.247 us; speedup vs baseline: 1.4577x; 1.1135x over previous
//
#include <hip/hip_runtime.h>
#include <math.h>

// ---------------------------------------------------------------------------
// MeshGraphUnet2 forward on gfx950.  Round 7: 1-hop branchless up-aggregation
// via precomputed remapped index array (idxU = nmap[idx]) + zero-row trick.
// Keeps: gemm3+LN fusion, ln+score fusion, LDS csum, 2-pass scan, XCD scatter.
// ---------------------------------------------------------------------------

typedef unsigned short u16;
typedef short bf16x8 __attribute__((ext_vector_type(8)));
typedef float f32x4 __attribute__((ext_vector_type(4)));

__device__ __forceinline__ unsigned int fkey(float f) {
  unsigned int b = __float_as_uint(f);
  return (b & 0x80000000u) ? ~b : (b | 0x80000000u);  // monotonic float->uint
}

__device__ __forceinline__ float gelu_f(float v) {
  return 0.5f * v * (1.0f + erff(v * 0.70710678118654752f));
}

__device__ __forceinline__ u16 f2bf(float f) {
  unsigned u = __float_as_uint(f);
  u = (u + 0x7FFFu + ((u >> 16) & 1u)) >> 16;  // round-nearest-even
  return (u16)u;
}
__device__ __forceinline__ float bf2f(u16 u) {
  return __uint_as_float(((unsigned)u) << 16);
}

// ---- level-0 scoring: key[i] = (float)(x[i,:].w) f64, valt = tanh(d/||w||)
__global__ void score_kernel(const float* __restrict__ x, const float* __restrict__ w,
                             float* __restrict__ key, float* __restrict__ valt, int n) {
  int wave = threadIdx.x >> 6, lane = threadIdx.x & 63;
  int i = blockIdx.x * 4 + wave;
  if (i >= n) return;
  float2 xv = *(const float2*)&x[(size_t)i * 128 + lane * 2];
  float2 wv = *(const float2*)&w[lane * 2];
  double d  = (double)xv.x * wv.x + (double)xv.y * wv.y;
  double nw = (double)wv.x * wv.x + (double)wv.y * wv.y;
  for (int o = 32; o; o >>= 1) { d += __shfl_down(d, o, 64); nw += __shfl_down(nw, o, 64); }
  if (lane == 0) {
    key[i]  = (float)d;
    valt[i] = (float)tanh(d / sqrt(nw));
  }
}

// precompute sqrt(||w||^2) per level with the SAME reduction tree as score_kernel
__global__ void wnorm_kernel(const float* __restrict__ poolw, double* __restrict__ sqn) {
  int lane = threadIdx.x & 63;
  for (int l = 0; l < 3; ++l) {
    float2 wv = *(const float2*)&poolw[l * 128 + lane * 2];
    double nw = (double)wv.x * wv.x + (double)wv.y * wv.y;
    for (int o = 32; o; o >>= 1) nw += __shfl_down(nw, o, 64);
    if (lane == 0) sqn[l] = sqrt(nw);
  }
}

// x0 f32 -> bf16
__global__ void xconv_kernel(const float* __restrict__ x, u16* __restrict__ xb, int n) {
  int gid = blockIdx.x * 256 + threadIdx.x;
  if (gid >= n * 32) return;
  float4 a = *(const float4*)&x[(size_t)gid * 4];
  *(ushort4*)&xb[(size_t)gid * 4] = make_ushort4(f2bf(a.x), f2bf(a.y), f2bf(a.z), f2bf(a.w));
}

// ---- histograms; csum accumulated in LDS per block, flushed with few atomics ----
__global__ void hist_hi_kernel(const float* __restrict__ key, int* __restrict__ hist,
                               int* __restrict__ csum, int n) {
  __shared__ int lc[256];
  lc[threadIdx.x] = 0;
  __syncthreads();
  int i = blockIdx.x * 256 + threadIdx.x;
  if (i < n) {
    unsigned b = fkey(key[i]) >> 16;
    atomicAdd(&hist[b], 1);
    atomicAdd(&lc[b >> 8], 1);
  }
  __syncthreads();
  int v = lc[threadIdx.x];
  if (v) atomicAdd(&csum[threadIdx.x], v);
}

__global__ void hist_lo_kernel(const float* __restrict__ key, const int* __restrict__ meta,
                               int* __restrict__ hist, int* __restrict__ csum, int n) {
  __shared__ int lc[256];
  lc[threadIdx.x] = 0;
  __syncthreads();
  int i = blockIdx.x * 256 + threadIdx.x;
  if (i < n) {
    unsigned u = fkey(key[i]);
    if ((u >> 16) == (unsigned)meta[0]) {
      unsigned b = u & 0xFFFFu;
      atomicAdd(&hist[b], 1);
      atomicAdd(&lc[b >> 8], 1);
    }
  }
  __syncthreads();
  int v = lc[threadIdx.x];
  if (v) atomicAdd(&csum[threadIdx.x], v);
}

__global__ void find_hi2_kernel(const int* __restrict__ hist, const int* __restrict__ csum,
                                int* __restrict__ meta, int k) {
  __shared__ int s[256];
  __shared__ int cSh, cumSh;
  int t = threadIdx.x;
  s[t] = csum[t];
  __syncthreads();
  if (t == 0) {
    int cum = 0, c = 0;
    for (int i = 255; i >= 0; --i) {
      if (cum + s[i] >= k) { c = i; break; }
      cum += s[i];
    }
    cSh = c; cumSh = cum;
  }
  __syncthreads();
  int c = cSh;
  s[t] = hist[c * 256 + t];
  __syncthreads();
  if (t == 0) {
    int cum = cumSh;
    for (int b = 255; b >= 0; --b) {
      int v = s[b];
      if (cum + v >= k) { meta[0] = c * 256 + b; meta[1] = k - cum; break; }
      cum += v;
    }
  }
}

__global__ void find_lo2_kernel(const int* __restrict__ hist, const int* __restrict__ csum,
                                int* __restrict__ meta) {
  __shared__ int s[256];
  __shared__ int cSh, cumSh;
  int t = threadIdx.x;
  int m = meta[1], B = meta[0];
  s[t] = csum[t];
  __syncthreads();
  if (t == 0) {
    int cum = 0, c = 0;
    for (int i = 255; i >= 0; --i) {
      if (cum + s[i] >= m) { c = i; break; }
      cum += s[i];
    }
    cSh = c; cumSh = cum;
  }
  __syncthreads();
  int c = cSh;
  s[t] = hist[c * 256 + t];
  __syncthreads();
  if (t == 0) {
    int cum = cumSh;
    for (int b = 255; b >= 0; --b) {
      int v = s[b];
      if (cum + v >= m) {
        meta[3] = (int)((((unsigned)B) << 16) | (unsigned)(c * 256 + b));
        meta[4] = m - cum;
        break;
      }
      cum += v;
    }
    meta[5] = 0;
  }
}

__global__ void tie_count_kernel(const float* __restrict__ key, const int* __restrict__ meta,
                                 int* __restrict__ tcnt, int n) {
  __shared__ int cnt[4];
  unsigned uT = (unsigned)meta[3];
  int i = blockIdx.x * 256 + threadIdx.x;
  bool tie = (i < n) && (fkey(key[i]) == uT);
  unsigned long long m = __ballot(tie);
  int lane = threadIdx.x & 63, w = threadIdx.x >> 6;
  if (lane == 0) cnt[w] = __popcll(m);
  __syncthreads();
  if (threadIdx.x == 0) tcnt[blockIdx.x] = cnt[0] + cnt[1] + cnt[2] + cnt[3];
}

// tie mark with self-computed block prefix (nb <= 256 guaranteed)
__global__ void tie_mark_kernel(const float* __restrict__ key, const int* __restrict__ meta,
                                const int* __restrict__ tcnt, unsigned char* __restrict__ selt,
                                int n) {
  __shared__ int red[256];
  __shared__ int woff[4];
  int t = threadIdx.x;
  red[t] = (t < (int)blockIdx.x) ? tcnt[t] : 0;
  __syncthreads();
  for (int s = 128; s; s >>= 1) {
    if (t < s) red[t] += red[t + s];
    __syncthreads();
  }
  int blockbase = red[0];
  unsigned uT = (unsigned)meta[3];
  int tsel = meta[4];
  int i = blockIdx.x * 256 + t;
  bool tie = (i < n) && (fkey(key[i]) == uT);
  unsigned long long m = __ballot(tie);
  int lane = t & 63, w = t >> 6;
  if (lane == 0) woff[w] = __popcll(m);
  __syncthreads();
  if (t == 0) {
    int c = 0;
    for (int q = 0; q < 4; ++q) { int v = woff[q]; woff[q] = c; c += v; }
  }
  __syncthreads();
  if (tie) {
    int pre = __popcll(m & ((1ull << lane) - 1ull));
    int rank = blockbase + woff[w] + pre;
    selt[i] = (rank < tsel) ? 1 : 0;
  }
}

__global__ void select_kernel(const float* __restrict__ key, const float* __restrict__ valt,
                              const unsigned char* __restrict__ selt, int* __restrict__ meta,
                              int* __restrict__ perm, float* __restrict__ vals,
                              int* __restrict__ nmap, int n, int k) {
  int i = blockIdx.x * 256 + threadIdx.x;
  if (i > n) return;
  if (i == n) { nmap[n] = k; return; }
  unsigned u  = fkey(key[i]);
  unsigned uT = (unsigned)meta[3];
  bool sel = (u > uT) || (u == uT && selt[i] != 0);
  if (sel) {
    int slot = atomicAdd(&meta[5], 1);
    perm[slot] = i; vals[slot] = valt[i]; nmap[i] = slot;
  } else {
    nmap[i] = k;
  }
}

__global__ void pool_kernel(const float* __restrict__ x, const int* __restrict__ perm,
                            const float* __restrict__ vals, float* __restrict__ xp, int k) {
  int gid = blockIdx.x * 256 + threadIdx.x;
  int t = gid >> 5;
  if (t >= k) return;
  int c = (gid & 31) << 2;
  float v = vals[t];
  float4 a = *(const float4*)&x[(size_t)perm[t] * 128 + c];
  a.x *= v; a.y *= v; a.z *= v; a.w *= v;
  *(float4*)&xp[(size_t)t * 128 + c] = a;
}

// remap + degree count fused (deg zeroed before)
__global__ void remap_deg_kernel(const int* __restrict__ s_in, const int* __restrict__ r_in,
                                 const int* __restrict__ nmap, int* __restrict__ s_out,
                                 int* __restrict__ r_out, int* __restrict__ deg, int E, int k) {
  int e = blockIdx.x * 256 + threadIdx.x;
  if (e >= E) return;
  int a = nmap[s_in[e]], b = nmap[r_in[e]];
  if (a == k || b == k) { a = k; b = k; }
  s_out[e] = a; r_out[e] = b;
  if (a < k) { atomicAdd(&deg[b], 1); atomicAdd(&deg[a], 1); }
}

__global__ void deg_kernel(const int* __restrict__ s, const int* __restrict__ r,
                           int* __restrict__ deg, int E, int n) {
  int e = blockIdx.x * 256 + threadIdx.x;
  if (e >= E) return;
  int ss = s[e];
  if (ss >= n) return;
  int rr = r[e];
  atomicAdd(&deg[rr], 1);
  atomicAdd(&deg[ss], 1);
}

// ---- 2-pass parallel exclusive scan (self-prefix final; nb <= 256) ----
__global__ void scan_part_kernel(const int* __restrict__ deg, int* __restrict__ bsum, int n) {
  __shared__ int l[256];
  int i = blockIdx.x * 256 + threadIdx.x;
  l[threadIdx.x] = (i < n) ? deg[i] : 0;
  __syncthreads();
  for (int s = 128; s; s >>= 1) {
    if (threadIdx.x < s) l[threadIdx.x] += l[threadIdx.x + s];
    __syncthreads();
  }
  if (threadIdx.x == 0) bsum[blockIdx.x] = l[0];
}

__global__ void scan_final_kernel(const int* __restrict__ deg, const int* __restrict__ bsum,
                                  int* __restrict__ off, int* __restrict__ cur, int n) {
  __shared__ int red[256];
  __shared__ int l[256];
  int i = blockIdx.x * 256 + threadIdx.x;
  int t = threadIdx.x;
  red[t] = (t < (int)blockIdx.x) ? bsum[t] : 0;
  __syncthreads();
  for (int s = 128; s; s >>= 1) {
    if (t < s) red[t] += red[t + s];
    __syncthreads();
  }
  int base = red[0];
  int v = (i < n) ? deg[i] : 0;
  l[t] = v;
  __syncthreads();
#pragma unroll
  for (int s = 1; s < 256; s <<= 1) {
    int add = (t >= s) ? l[t - s] : 0;
    __syncthreads();
    l[t] += add;
    __syncthreads();
  }
  int incl = l[t];
  if (i < n) {
    int e = base + incl - v;
    off[i] = e; cur[i] = e;
    if (i == n - 1) off[n] = base + incl;
  }
}

__global__ void csr_scatter_kernel(const int* __restrict__ s, const int* __restrict__ r,
                                   int* __restrict__ cur, int* __restrict__ idx, int E, int n) {
  int e = blockIdx.x * 256 + threadIdx.x;
  if (e >= E) return;
  int ss = s[e];
  if (ss >= n) return;
  int rr = r[e];
  idx[atomicAdd(&cur[rr], 1)] = ss;
  idx[atomicAdd(&cur[ss], 1)] = rr;
}

// XCD-partitioned scatter (8 node-range groups, group = blockIdx&7)
__global__ void csr_scatter_part_kernel(const int* __restrict__ s, const int* __restrict__ r,
                                        int* __restrict__ cur, int* __restrict__ idx,
                                        int E, int n, int rshift) {
  int g = blockIdx.x & 7;
  int nb = gridDim.x >> 3;
  int bb = blockIdx.x >> 3;
  int lo = g << rshift, hi = (g + 1) << rshift;
  int stride = nb * 256;
  for (int e = bb * 256 + threadIdx.x; e < E; e += stride) {
    int ss = s[e];
    if (ss >= n) continue;
    int rr = r[e];
    if (rr >= lo && rr < hi) idx[atomicAdd(&cur[rr], 1)] = ss;
    if (ss >= lo && ss < hi) idx[atomicAdd(&cur[ss], 1)] = rr;
  }
}

// idxU[j] = nmapL[idx[j]] for j < off[n]  (1-hop remap for the up gather)
__global__ void idxup_kernel(const int* __restrict__ idx, const int* __restrict__ nmapL,
                             const int* __restrict__ offn, int* __restrict__ idxu, int maxlen) {
  int j = blockIdx.x * 256 + threadIdx.x;
  if (j >= maxlen) return;
  int len = offn[0];
  if (j >= len) return;
  idxu[j] = nmapL[idx[j]];
}

// ---- down-path f32 aggregation (C=128) ----
__global__ void agg_kernel(const float* __restrict__ x, const int* __restrict__ off,
                           const int* __restrict__ idx, float* __restrict__ agg, int n) {
  int wave = threadIdx.x >> 6, lane = threadIdx.x & 63;
  int v = blockIdx.x * 4 + wave;
  if (v >= n) return;
  int lo = off[v], hi = off[v + 1];
  int c = lane * 2;
  float ax = 0.f, ay = 0.f;
  int j = lo;
  for (; j + 4 <= hi; j += 4) {
    int u0 = idx[j], u1 = idx[j + 1], u2 = idx[j + 2], u3 = idx[j + 3];
    float2 a0 = *(const float2*)&x[(size_t)u0 * 128 + c];
    float2 a1 = *(const float2*)&x[(size_t)u1 * 128 + c];
    float2 a2 = *(const float2*)&x[(size_t)u2 * 128 + c];
    float2 a3 = *(const float2*)&x[(size_t)u3 * 128 + c];
    ax += a0.x + a1.x + a2.x + a3.x;
    ay += a0.y + a1.y + a2.y + a3.y;
  }
  for (; j < hi; ++j) {
    int u = idx[j];
    float2 a = *(const float2*)&x[(size_t)u * 128 + c];
    ax += a.x; ay += a.y;
  }
  float2 o; o.x = ax; o.y = ay;
  *(float2*)&agg[(size_t)v * 128 + c] = o;
}

// ---- fused up-path aggregation, 1-hop branchless ----
// agg[v] = [ sum_{u in N(v)} res_bf[u]  |  sum_{j} xd_bf[idxU[j]] ]
// xd_bf has a zero row at index k (dropped nodes), so no guard needed.
// Lanes 0-31: res half via idx; lanes 32-63: up half via idxU.
__global__ void agg_up_kernel(const u16* __restrict__ res_bf, const u16* __restrict__ xd_bf,
                              const int* __restrict__ idxR, const int* __restrict__ idxU,
                              const int* __restrict__ off, u16* __restrict__ agg, int n) {
  int wave = threadIdx.x >> 6, lane = threadIdx.x & 63;
  int v = blockIdx.x * 4 + wave;
  if (v >= n) return;
  int lo = off[v], hi = off[v + 1];
  bool hiHalf = lane >= 32;
  const int* ia = hiHalf ? idxU : idxR;
  const u16* base = hiHalf ? xd_bf : res_bf;
  int c4 = (lane & 31) << 2;
  float a0 = 0.f, a1 = 0.f, a2 = 0.f, a3 = 0.f;
  int j = lo;
  for (; j + 8 <= hi; j += 8) {
    int us[8];
#pragma unroll
    for (int q = 0; q < 8; ++q) us[q] = ia[j + q];
#pragma unroll
    for (int q = 0; q < 8; ++q) {
      ushort4 b = *(const ushort4*)&base[(size_t)us[q] * 128 + c4];
      a0 += bf2f(b.x); a1 += bf2f(b.y); a2 += bf2f(b.z); a3 += bf2f(b.w);
    }
  }
  for (; j < hi; ++j) {
    ushort4 b = *(const ushort4*)&base[(size_t)ia[j] * 128 + c4];
    a0 += bf2f(b.x); a1 += bf2f(b.y); a2 += bf2f(b.z); a3 += bf2f(b.w);
  }
  size_t basew = (size_t)v * 256 + (hiHalf ? 128 : 0) + c4;
  *(ushort4*)&agg[basew] = make_ushort4(f2bf(a0), f2bf(a1), f2bf(a2), f2bf(a3));
}

// ---- down-path f32 GEMM (CIN=128), 32-row tile ----
template <bool GELU>
__global__ __launch_bounds__(256) void gemm_kernel(const float* __restrict__ A,
                                                   const float* __restrict__ W,
                                                   const float* __restrict__ bias,
                                                   float* __restrict__ out, int n) {
  __shared__ float As[32 * 32];
  __shared__ float Ws[32 * 128];
  int t = threadIdx.x;
  int row0 = blockIdx.x * 32;
  int colg = (t & 31) << 2;
  int rowg = (t >> 5) << 2;
  float acc[4][4];
#pragma unroll
  for (int i = 0; i < 4; ++i)
#pragma unroll
    for (int j = 0; j < 4; ++j) acc[i][j] = 0.f;

  for (int k0 = 0; k0 < 128; k0 += 32) {
    __syncthreads();
    {
      int ar = t >> 3, ac = (t & 7) << 2;
      float4 av = make_float4(0.f, 0.f, 0.f, 0.f);
      if (row0 + ar < n) av = *(const float4*)&A[(size_t)(row0 + ar) * 128 + k0 + ac];
      *(float4*)&As[ar * 32 + ac] = av;
    }
#pragma unroll
    for (int l = 0; l < 4; ++l) {
      int id = t + l * 256;
      int kk = id >> 5, wc = (id & 31) << 2;
      *(float4*)&Ws[kk * 128 + wc] = *(const float4*)&W[(size_t)(k0 + kk) * 128 + wc];
    }
    __syncthreads();
#pragma unroll
    for (int kk = 0; kk < 32; kk += 4) {
      float4 wv[4];
#pragma unroll
      for (int j = 0; j < 4; ++j) wv[j] = *(const float4*)&Ws[(kk + j) * 128 + colg];
#pragma unroll
      for (int i = 0; i < 4; ++i) {
        float4 av = *(const float4*)&As[(rowg + i) * 32 + kk];
        acc[i][0] += av.x * wv[0].x + av.y * wv[1].x + av.z * wv[2].x + av.w * wv[3].x;
        acc[i][1] += av.x * wv[0].y + av.y * wv[1].y + av.z * wv[2].y + av.w * wv[3].y;
        acc[i][2] += av.x * wv[0].z + av.y * wv[1].z + av.z * wv[2].z + av.w * wv[3].z;
        acc[i][3] += av.x * wv[0].w + av.y * wv[1].w + av.z * wv[2].w + av.w * wv[3].w;
      }
    }
  }
  float4 bv = *(const float4*)&bias[colg];
#pragma unroll
  for (int i = 0; i < 4; ++i) {
    int rr = row0 + rowg + i;
    if (rr < n) {
      float4 o = make_float4(acc[i][0] + bv.x, acc[i][1] + bv.y, acc[i][2] + bv.z, acc[i][3] + bv.w);
      if (GELU) { o.x = gelu_f(o.x); o.y = gelu_f(o.y); o.z = gelu_f(o.z); o.w = gelu_f(o.w); }
      *(float4*)&out[(size_t)rr * 128 + colg] = o;
    }
  }
}

// ---- up-path MFMA GEMM (gelu, bf16 out) ----
template <int K>
__global__ __launch_bounds__(256) void gemm_mfma_kernel(const u16* __restrict__ A,
                                                        const u16* __restrict__ WT,
                                                        const float* __restrict__ bias,
                                                        u16* __restrict__ out, int n) {
  __shared__ u16 As[64 * 72];
  __shared__ u16 Ws[128 * 72];
  int t = threadIdx.x;
  int lane = t & 63, wave = t >> 6;
  int row0 = blockIdx.x * 64;
  f32x4 acc[8];
#pragma unroll
  for (int i = 0; i < 8; ++i) acc[i] = (f32x4){0.f, 0.f, 0.f, 0.f};

  for (int k0 = 0; k0 < K; k0 += 64) {
    __syncthreads();
#pragma unroll
    for (int i = 0; i < 2; ++i) {
      int c = t + i * 256;
      int r = c >> 3, seg = c & 7;
      bf16x8 v = {0, 0, 0, 0, 0, 0, 0, 0};
      if (row0 + r < n) v = *(const bf16x8*)&A[(size_t)(row0 + r) * K + k0 + seg * 8];
      *(bf16x8*)&As[r * 72 + seg * 8] = v;
    }
#pragma unroll
    for (int i = 0; i < 4; ++i) {
      int c = t + i * 256;
      int r = c >> 3, seg = c & 7;
      *(bf16x8*)&Ws[r * 72 + seg * 8] = *(const bf16x8*)&WT[(size_t)r * K + k0 + seg * 8];
    }
    __syncthreads();
#pragma unroll
    for (int kk = 0; kk < 64; kk += 32) {
      bf16x8 a = *(const bf16x8*)&As[(wave * 16 + (lane & 15)) * 72 + kk + (lane >> 4) * 8];
#pragma unroll
      for (int ct = 0; ct < 8; ++ct) {
        bf16x8 b = *(const bf16x8*)&Ws[(ct * 16 + (lane & 15)) * 72 + kk + (lane >> 4) * 8];
        acc[ct] = __builtin_amdgcn_mfma_f32_16x16x32_bf16(a, b, acc[ct], 0, 0, 0);
      }
    }
  }
  int colb = lane & 15, rquad = lane >> 4;
#pragma unroll
  for (int ct = 0; ct < 8; ++ct) {
#pragma unroll
    for (int r = 0; r < 4; ++r) {
      int row = row0 + wave * 16 + rquad * 4 + r;
      if (row < n) {
        int col = ct * 16 + colb;
        out[(size_t)row * 128 + col] = f2bf(gelu_f(acc[ct][r] + bias[col]));
      }
    }
  }
}

// ---- up-path MFMA GEMM3 + fused LayerNorm ----
template <bool WF32, bool WBF>
__global__ __launch_bounds__(256) void gemm_mfma_ln_kernel(
    const u16* __restrict__ A, const u16* __restrict__ WT, const float* __restrict__ bias,
    const float* __restrict__ g, const float* __restrict__ beta,
    float* __restrict__ out, u16* __restrict__ outbf, int n) {
  __shared__ u16 As[64 * 72];
  __shared__ u16 Ws[128 * 72];
  int t = threadIdx.x;
  int lane = t & 63, wave = t >> 6;
  int row0 = blockIdx.x * 64;
  f32x4 acc[8];
#pragma unroll
  for (int i = 0; i < 8; ++i) acc[i] = (f32x4){0.f, 0.f, 0.f, 0.f};

  for (int k0 = 0; k0 < 128; k0 += 64) {
    __syncthreads();
#pragma unroll
    for (int i = 0; i < 2; ++i) {
      int c = t + i * 256;
      int r = c >> 3, seg = c & 7;
      bf16x8 v = {0, 0, 0, 0, 0, 0, 0, 0};
      if (row0 + r < n) v = *(const bf16x8*)&A[(size_t)(row0 + r) * 128 + k0 + seg * 8];
      *(bf16x8*)&As[r * 72 + seg * 8] = v;
    }
#pragma unroll
    for (int i = 0; i < 4; ++i) {
      int c = t + i * 256;
      int r = c >> 3, seg = c & 7;
      *(bf16x8*)&Ws[r * 72 + seg * 8] = *(const bf16x8*)&WT[(size_t)r * 128 + k0 + seg * 8];
    }
    __syncthreads();
#pragma unroll
    for (int kk = 0; kk < 64; kk += 32) {
      bf16x8 a = *(const bf16x8*)&As[(wave * 16 + (lane & 15)) * 72 + kk + (lane >> 4) * 8];
#pragma unroll
      for (int ct = 0; ct < 8; ++ct) {
        bf16x8 b = *(const bf16x8*)&Ws[(ct * 16 + (lane & 15)) * 72 + kk + (lane >> 4) * 8];
        acc[ct] = __builtin_amdgcn_mfma_f32_16x16x32_bf16(a, b, acc[ct], 0, 0, 0);
      }
    }
  }
  int colb = lane & 15, rquad = lane >> 4;
  float bv[8], gv[8], bev[8];
#pragma unroll
  for (int ct = 0; ct < 8; ++ct) {
    int col = ct * 16 + colb;
    bv[ct] = bias[col]; gv[ct] = g[col]; bev[ct] = beta[col];
  }
#pragma unroll
  for (int r = 0; r < 4; ++r) {
    float s1 = 0.f;
#pragma unroll
    for (int ct = 0; ct < 8; ++ct) s1 += acc[ct][r] + bv[ct];
#pragma unroll
    for (int o = 1; o <= 8; o <<= 1) s1 += __shfl_xor(s1, o, 64);
    float mu = s1 * (1.0f / 128.0f);
    float s2 = 0.f;
#pragma unroll
    for (int ct = 0; ct < 8; ++ct) { float d = acc[ct][r] + bv[ct] - mu; s2 += d * d; }
#pragma unroll
    for (int o = 1; o <= 8; o <<= 1) s2 += __shfl_xor(s2, o, 64);
    float rs = rsqrtf(s2 * (1.0f / 128.0f) + 1e-5f);
    int row = row0 + wave * 16 + rquad * 4 + r;
    if (row < n) {
#pragma unroll
      for (int ct = 0; ct < 8; ++ct) {
        int col = ct * 16 + colb;
        float o = gv[ct] * (acc[ct][r] + bv[ct] - mu) * rs + bev[ct];
        if (WF32) out[(size_t)row * 128 + col] = o;
        if (WBF)  outbf[(size_t)row * 128 + col] = f2bf(o);
      }
    }
  }
}

// fused convert+transpose of all 9 up-path weights, one dispatch
__global__ void wconv_all_kernel(const float* __restrict__ uW1, const float* __restrict__ uW2,
                                 const float* __restrict__ uW3, u16* __restrict__ wt1,
                                 u16* __restrict__ wt2, u16* __restrict__ wt3) {
  int i = blockIdx.x * 256 + threadIdx.x;
  if (i >= 3 * 65536) return;
  int lvl = i >> 16, rem = i & 65535;
  if (rem < 32768) {  // W1: [256][128] -> [128][256]
    int k = rem >> 7, c = rem & 127;
    wt1[(size_t)lvl * 32768 + c * 256 + k] = f2bf(uW1[(size_t)lvl * 32768 + rem]);
  } else if (rem < 49152) {
    int j = rem - 32768; int k = j >> 7, c = j & 127;
    wt2[(size_t)lvl * 16384 + c * 128 + k] = f2bf(uW2[(size_t)lvl * 16384 + j]);
  } else {
    int j = rem - 49152; int k = j >> 7, c = j & 127;
    wt3[(size_t)lvl * 16384 + c * 128 + k] = f2bf(uW3[(size_t)lvl * 16384 + j]);
  }
}

// ---- down-path LN (+ optional bf16 copy, + optional fused next-level score) ----
template <bool SCORE, bool WBF>
__global__ void ln_kernel(const float* __restrict__ h, const float* __restrict__ g,
                          const float* __restrict__ beta, float* __restrict__ out,
                          u16* __restrict__ outbf, const float* __restrict__ wnext,
                          const double* __restrict__ sqn, float* __restrict__ key,
                          float* __restrict__ valt, int n) {
  int wave = threadIdx.x >> 6, lane = threadIdx.x & 63;
  int i = blockIdx.x * 4 + wave;
  if (i >= n) return;
  float2 hv = *(const float2*)&h[(size_t)i * 128 + lane * 2];
  float s = hv.x + hv.y;
  for (int o = 32; o; o >>= 1) s += __shfl_down(s, o, 64);
  float mu = __shfl(s, 0, 64) * (1.0f / 128.0f);
  float dx = hv.x - mu, dy = hv.y - mu;
  float q = dx * dx + dy * dy;
  for (int o = 32; o; o >>= 1) q += __shfl_down(q, o, 64);
  float var = __shfl(q, 0, 64) * (1.0f / 128.0f);
  float rs = rsqrtf(var + 1e-5f);
  float2 gv = *(const float2*)&g[lane * 2];
  float2 bv = *(const float2*)&beta[lane * 2];
  float2 o2; o2.x = gv.x * dx * rs + bv.x; o2.y = gv.y * dy * rs + bv.y;
  *(float2*)&out[(size_t)i * 128 + lane * 2] = o2;
  if (WBF)
    *(ushort2*)&outbf[(size_t)i * 128 + lane * 2] = make_ushort2(f2bf(o2.x), f2bf(o2.y));
  if (SCORE) {
    float2 wv = *(const float2*)&wnext[lane * 2];
    double d = (double)o2.x * wv.x + (double)o2.y * wv.y;
    for (int o = 32; o; o >>= 1) d += __shfl_down(d, o, 64);
    if (lane == 0) {
      key[i]  = (float)d;
      valt[i] = (float)tanh(d / sqn[0]);
    }
  }
}

// ---------------------------------------------------------------------------

static inline int cdiv(int a, int b) { return (a + b - 1) / b; }

extern "C" void kernel_launch(void* const* d_in, const int* in_sizes, int n_in,
                              void* d_out, int out_size, void* d_ws, size_t ws_size,
                              hipStream_t stream) {
  const float* x0   = (const float*)d_in[0];
  const int*   snd  = (const int*)d_in[1];
  const int*   rcv  = (const int*)d_in[2];
  const float* poolw = (const float*)d_in[3];
  const float* dW1 = (const float*)d_in[4];
  const float* db1 = (const float*)d_in[5];
  const float* dW2 = (const float*)d_in[6];
  const float* db2 = (const float*)d_in[7];
  const float* dW3 = (const float*)d_in[8];
  const float* db3 = (const float*)d_in[9];
  const float* dg  = (const float*)d_in[10];
  const float* dbe = (const float*)d_in[11];
  const float* uW1 = (const float*)d_in[12];
  const float* ub1 = (const float*)d_in[13];
  const float* uW2 = (const float*)d_in[14];
  const float* ub2 = (const float*)d_in[15];
  const float* uW3 = (const float*)d_in[16];
  const float* ub3 = (const float*)d_in[17];
  const float* ug  = (const float*)d_in[18];
  const float* ube = (const float*)d_in[19];

  const int N0 = in_sizes[0] / 128;
  const int E  = in_sizes[1];
  const int N1 = (N0 + 1) / 2, N2 = (N1 + 1) / 2, N3 = (N2 + 1) / 2;

  // ---- workspace carve ----
  char* p = (char*)d_ws;
  auto alloc = [&](size_t bytes) -> void* {
    void* r = (void*)p;
    p += (bytes + 255) & ~(size_t)255;
    return r;
  };
  float* key  = (float*)alloc((size_t)N0 * 4);
  float* valt = (float*)alloc((size_t)N0 * 4);
  int*   hist = (int*)alloc((size_t)(2 * 65536 + 512) * 4);
  int*   csum_hi = hist + 2 * 65536;
  int*   csum_lo = hist + 2 * 65536 + 256;
  int*   meta = (int*)alloc(64 * 4);
  int*   tcnt = (int*)alloc(512 * 4);
  int*   bsum = (int*)alloc(256 * 4);
  unsigned char* selt = (unsigned char*)alloc((size_t)N0);
  int*   nm1 = (int*)alloc((size_t)(N0 + 1) * 4);
  int*   nm2 = (int*)alloc((size_t)(N1 + 1) * 4);
  int*   nm3 = (int*)alloc((size_t)(N2 + 1) * 4);
  int*   perm0 = (int*)alloc((size_t)N1 * 4);
  int*   perm1 = (int*)alloc((size_t)N2 * 4);
  int*   perm2 = (int*)alloc((size_t)N3 * 4);
  float* vals  = (float*)alloc((size_t)N1 * 4);
  double* sqn  = (double*)alloc(8 * 8);
  // edge lists (down only; h2b aliases this region during up)
  int* s1 = (int*)alloc((size_t)E * 4); int* r1 = (int*)alloc((size_t)E * 4);
  int* s2 = (int*)alloc((size_t)E * 4); int* r2 = (int*)alloc((size_t)E * 4);
  int* s3 = (int*)alloc((size_t)E * 4); int* r3 = (int*)alloc((size_t)E * 4);
  float* x1 = (float*)alloc((size_t)N1 * 128 * 4);
  float* x2 = (float*)alloc((size_t)N2 * 128 * 4);
  float* x3 = (float*)alloc((size_t)N3 * 128 * 4);
  float* xp = (float*)alloc((size_t)N1 * 128 * 4);   // down only; h1b aliases in up
  float* aggf = (float*)alloc((size_t)N1 * 128 * 4);
  float* h1f  = (float*)alloc((size_t)N1 * 128 * 4);
  float* h2f  = (float*)alloc((size_t)N1 * 128 * 4);
  u16* agg_bf = (u16*)alloc((size_t)N0 * 256 * 2);
  u16* res0_bf = (u16*)alloc((size_t)N0 * 128 * 2);
  u16* res1_bf = (u16*)alloc((size_t)N1 * 128 * 2);
  u16* res2_bf = (u16*)alloc((size_t)N2 * 128 * 2);
  u16* x3_bf   = (u16*)alloc((size_t)(N3 + 1) * 128 * 2);  // +1 zero row
  u16* xu2_bf  = (u16*)alloc((size_t)(N2 + 1) * 128 * 2);  // +1 zero row
  u16* xu1_bf  = (u16*)alloc((size_t)(N1 + 1) * 128 * 2);  // +1 zero row
  u16* wt1 = (u16*)alloc((size_t)3 * 128 * 256 * 2);
  u16* wt2 = (u16*)alloc((size_t)3 * 128 * 128 * 2);
  u16* wt3 = (u16*)alloc((size_t)3 * 128 * 128 * 2);
  int* off0 = (int*)alloc((size_t)(N0 + 1) * 4); int* cur0 = (int*)alloc((size_t)N0 * 4);
  int* idx0 = (int*)alloc((size_t)2 * E * 4);
  int* off1 = (int*)alloc((size_t)(N1 + 1) * 4); int* cur1 = (int*)alloc((size_t)N1 * 4);
  int* idx1 = (int*)alloc((size_t)2 * E * 4);
  int* off2 = (int*)alloc((size_t)(N2 + 1) * 4); int* cur2 = (int*)alloc((size_t)N2 * 4);
  int* idx2 = (int*)alloc((size_t)2 * E * 4);
  int* off3 = (int*)alloc((size_t)(N3 + 1) * 4); int* cur3 = (int*)alloc((size_t)N3 * 4);
  int* idx3 = (int*)alloc((size_t)2 * E * 4);
  int* idxu0 = (int*)alloc((size_t)2 * E * 4);   // nmap-remapped idx0 (for up lvl 2)
  int* idxu1 = (int*)alloc((size_t)2 * E * 4);   // remapped idx1 (up lvl 1)
  int* idxu2 = (int*)alloc((size_t)2 * E * 4);   // remapped idx2 (up lvl 0)

  // phase-disjoint aliases (up-phase bf16 activations over dead down buffers)
  u16* h1b = (u16*)xp;              // N0*128*2 over xp
  u16* h2b = (u16*)s1;              // N0*128*2 over s1..r3

  auto run_scan = [&](int* curB, int* offB, int n) {
    int nb = cdiv(n, 256);
    scan_part_kernel<<<nb, 256, 0, stream>>>(curB, bsum, n);
    scan_final_kernel<<<nb, 256, 0, stream>>>(curB, bsum, offB, curB, n);
  };

  auto run_scatter = [&](const int* s, const int* r, int* cur, int* idx, int n) {
    if (n >= 16384) {
      int nb = cdiv(E, 2048);
      int per = cdiv(n, 8);
      int rshift = 0;
      while ((1 << rshift) < per) ++rshift;
      csr_scatter_part_kernel<<<nb * 8, 256, 0, stream>>>(s, r, cur, idx, E, n, rshift);
    } else {
      csr_scatter_kernel<<<cdiv(E, 256), 256, 0, stream>>>(s, r, cur, idx, E, n);
    }
  };

  // ---- one-time converts + zero rows for the up gather ----
  wconv_all_kernel<<<cdiv(3 * 65536, 256), 256, 0, stream>>>(uW1, uW2, uW3, wt1, wt2, wt3);
  xconv_kernel<<<cdiv(N0 * 32, 256), 256, 0, stream>>>(x0, res0_bf, N0);
  wnorm_kernel<<<1, 64, 0, stream>>>(poolw, sqn);
  hipMemsetAsync(x3_bf + (size_t)N3 * 128, 0, 256, stream);
  hipMemsetAsync(xu2_bf + (size_t)N2 * 128, 0, 256, stream);
  hipMemsetAsync(xu1_bf + (size_t)N1 * 128, 0, 256, stream);

  // ---- level-0 CSR (for the final up step) ----
  hipMemsetAsync(cur0, 0, (size_t)N0 * 4, stream);
  deg_kernel<<<cdiv(E, 256), 256, 0, stream>>>(snd, rcv, cur0, E, N0);
  run_scan(cur0, off0, N0);
  run_scatter(snd, rcv, cur0, idx0, N0);

  // ---- generic down step (f32 exact; feeds top-k selection) ----
  auto down_step = [&](int n, int k, const float* xcur, const int* sin, const int* rin,
                       int* sout, int* rout, int* permL, int* nmL, float* xnext,
                       u16* xnext_bf, int lvl, int* offL, int* curL, int* idxL) {
    int nb = cdiv(n, 256);
    hipMemsetAsync(hist, 0, (size_t)(2 * 65536 + 512) * 4, stream);
    hist_hi_kernel<<<nb, 256, 0, stream>>>(key, hist, csum_hi, n);
    find_hi2_kernel<<<1, 256, 0, stream>>>(hist, csum_hi, meta, k);
    hist_lo_kernel<<<nb, 256, 0, stream>>>(key, meta, hist + 65536, csum_lo, n);
    find_lo2_kernel<<<1, 256, 0, stream>>>(hist + 65536, csum_lo, meta);
    tie_count_kernel<<<nb, 256, 0, stream>>>(key, meta, tcnt, n);
    tie_mark_kernel<<<nb, 256, 0, stream>>>(key, meta, tcnt, selt, n);
    select_kernel<<<cdiv(n + 1, 256), 256, 0, stream>>>(key, valt, selt, meta, permL, vals, nmL, n, k);
    pool_kernel<<<cdiv(k * 32, 256), 256, 0, stream>>>(xcur, permL, vals, xp, k);
    hipMemsetAsync(curL, 0, (size_t)k * 4, stream);
    remap_deg_kernel<<<cdiv(E, 256), 256, 0, stream>>>(sin, rin, nmL, sout, rout, curL, E, k);
    run_scan(curL, offL, k);
    run_scatter(sout, rout, curL, idxL, k);
    agg_kernel<<<cdiv(k, 4), 256, 0, stream>>>(xp, offL, idxL, aggf, k);
    gemm_kernel<true><<<cdiv(k, 32), 256, 0, stream>>>(
        aggf, dW1 + (size_t)lvl * 128 * 128, db1 + (size_t)lvl * 128, h1f, k);
    gemm_kernel<true><<<cdiv(k, 32), 256, 0, stream>>>(
        h1f, dW2 + (size_t)lvl * 128 * 128, db2 + (size_t)lvl * 128, h2f, k);
    gemm_kernel<false><<<cdiv(k, 32), 256, 0, stream>>>(
        h2f, dW3 + (size_t)lvl * 128 * 128, db3 + (size_t)lvl * 128, h1f, k);
    if (lvl < 2)
      ln_kernel<true, true><<<cdiv(k, 4), 256, 0, stream>>>(
          h1f, dg + (size_t)lvl * 128, dbe + (size_t)lvl * 128, xnext, xnext_bf,
          poolw + (size_t)(lvl + 1) * 128, sqn + (lvl + 1), key, valt, k);
    else
      ln_kernel<false, true><<<cdiv(k, 4), 256, 0, stream>>>(
          h1f, dg + (size_t)lvl * 128, dbe + (size_t)lvl * 128, xnext, xnext_bf,
          nullptr, nullptr, nullptr, nullptr, k);
  };

  // level-0 score from x0
  score_kernel<<<cdiv(N0, 4), 256, 0, stream>>>(x0, poolw, key, valt, N0);
  down_step(N0, N1, x0, snd, rcv, s1, r1, perm0, nm1, x1, res1_bf, 0, off1, cur1, idx1);
  down_step(N1, N2, x1, s1, r1, s2, r2, perm1, nm2, x2, res2_bf, 1, off2, cur2, idx2);
  down_step(N2, N3, x2, s2, r2, s3, r3, perm2, nm3, x3, x3_bf, 2, off3, cur3, idx3);

  // ---- remapped up-gather indices (1-hop) ----
  idxup_kernel<<<cdiv(2 * E, 256), 256, 0, stream>>>(idx2, nm3, off2 + N2, idxu2, 2 * E);
  idxup_kernel<<<cdiv(2 * E, 256), 256, 0, stream>>>(idx1, nm2, off1 + N1, idxu1, 2 * E);
  idxup_kernel<<<cdiv(2 * E, 256), 256, 0, stream>>>(idx0, nm1, off0 + N0, idxu0, 2 * E);

  // ---- generic up step (bf16 path, fused agg + fused LN) ----
  auto up_step = [&](int n, const u16* resb, const u16* xdb, int lvl,
                     const int* offL, const int* idxL, const int* idxUL,
                     bool wantF32, float* outF32, u16* outBF) {
    agg_up_kernel<<<cdiv(n, 4), 256, 0, stream>>>(resb, xdb, idxL, idxUL, offL, agg_bf, n);
    gemm_mfma_kernel<256><<<cdiv(n, 64), 256, 0, stream>>>(
        agg_bf, wt1 + (size_t)lvl * 128 * 256, ub1 + (size_t)lvl * 128, h1b, n);
    gemm_mfma_kernel<128><<<cdiv(n, 64), 256, 0, stream>>>(
        h1b, wt2 + (size_t)lvl * 128 * 128, ub2 + (size_t)lvl * 128, h2b, n);
    if (wantF32)
      gemm_mfma_ln_kernel<true, false><<<cdiv(n, 64), 256, 0, stream>>>(
          h2b, wt3 + (size_t)lvl * 128 * 128, ub3 + (size_t)lvl * 128,
          ug + (size_t)lvl * 128, ube + (size_t)lvl * 128, outF32, nullptr, n);
    else
      gemm_mfma_ln_kernel<false, true><<<cdiv(n, 64), 256, 0, stream>>>(
          h2b, wt3 + (size_t)lvl * 128 * 128, ub3 + (size_t)lvl * 128,
          ug + (size_t)lvl * 128, ube + (size_t)lvl * 128, nullptr, outBF, n);
  };

  up_step(N2, res2_bf, x3_bf,  0, off2, idx2, idxu2, false, nullptr, xu2_bf);
  up_step(N1, res1_bf, xu2_bf, 1, off1, idx1, idxu1, false, nullptr, xu1_bf);
  up_step(N0, res0_bf, xu1_bf, 2, off0, idx0, idxu0, true, (float*)d_out, nullptr);

  (void)n_in; (void)out_size; (void)ws_size;
}